// Round 5
// baseline (426.362 us; speedup 1.0000x reference)
//
#include <hip/hip_runtime.h>

#define N_NODES 32768
#define N_EDGES 262144
#define NB      512
#define D       64
#define DE      16
#define NEXP    8

typedef __attribute__((ext_vector_type(8))) short  short8v;
typedef __attribute__((ext_vector_type(4))) float  floatx4;

static __device__ __forceinline__ unsigned short f2bf(float f) {
  unsigned int u = __float_as_uint(f);
  u += 0x7FFFu + ((u >> 16) & 1u);
  return (unsigned short)(u >> 16);
}

// ---------------- sort edges by dst ----------------

__global__ void hist_kernel(const int* __restrict__ dst, int* __restrict__ counts) {
  int i = blockIdx.x * blockDim.x + threadIdx.x;
  if (i < N_EDGES) atomicAdd(&counts[dst[i]], 1);
}

__global__ void scan1_kernel(const int* __restrict__ counts, int* __restrict__ offsets,
                             int* __restrict__ bsums) {
  __shared__ int sm[256];
  int t = threadIdx.x, i = blockIdx.x * 256 + t;
  int v = counts[i];
  sm[t] = v;
  __syncthreads();
  for (int off = 1; off < 256; off <<= 1) {
    int u = (t >= off) ? sm[t - off] : 0;
    __syncthreads();
    sm[t] += u;
    __syncthreads();
  }
  offsets[i] = sm[t] - v;              // in-block exclusive
  if (t == 255) bsums[blockIdx.x] = sm[255];
}

__global__ void scan2_kernel(int* __restrict__ bsums) {
  __shared__ int sm[128];
  int t = threadIdx.x;
  int v = bsums[t];
  sm[t] = v;
  __syncthreads();
  for (int off = 1; off < 128; off <<= 1) {
    int u = (t >= off) ? sm[t - off] : 0;
    __syncthreads();
    sm[t] += u;
    __syncthreads();
  }
  bsums[t] = sm[t] - v;                // exclusive block offsets
}

__global__ void scan3_kernel(int* __restrict__ offsets, const int* __restrict__ bsums,
                             int* __restrict__ cursor) {
  int i = blockIdx.x * 256 + threadIdx.x;
  int v = offsets[i] + bsums[blockIdx.x];
  offsets[i] = v;
  cursor[i]  = v;
  if (i == 0) offsets[N_NODES] = N_EDGES;
}

// scatter sorted payload (+ fused weight pack in spare thread range)
__global__ void scatter_kernel(const int* __restrict__ dst, const int* __restrict__ src,
                               const float4* __restrict__ ea4, int* __restrict__ cursor,
                               int* __restrict__ sorted_src, float4* __restrict__ sea4,
                               const float* __restrict__ ex_W1, const float* __restrict__ ex_W2,
                               unsigned short* __restrict__ wpk) {
  int i = blockIdx.x * blockDim.x + threadIdx.x;
  if (i < N_EDGES) {
    int p = atomicAdd(&cursor[dst[i]], 1);
    sorted_src[p] = src[i];
    float4 a = ea4[(size_t)i * 4 + 0];
    float4 b = ea4[(size_t)i * 4 + 1];
    float4 c = ea4[(size_t)i * 4 + 2];
    float4 d = ea4[(size_t)i * 4 + 3];
    sea4[(size_t)p * 4 + 0] = a;
    sea4[(size_t)p * 4 + 1] = b;
    sea4[(size_t)p * 4 + 2] = c;
    sea4[(size_t)p * 4 + 3] = d;
  }
  if (i < NEXP * 2 * D * D) {          // wpk[je][mat][col][k] = W_mat_je[k][col]
    int je  = i >> 13;
    int rem = i & 8191;
    int mat = rem >> 12;
    int cd  = rem & 4095;
    int col = cd >> 6, k = cd & 63;
    const float* W = mat ? ex_W2 : ex_W1;
    wpk[i] = f2bf(W[je * 4096 + k * 64 + col]);
  }
}

// ---------------- agg v4: We in LDS, multi-node blocks, batched edge loads ----------------
// wave = node (lane = d), 4 nodes per wave, 8 waves per block, 32 nodes per block.

__global__ __launch_bounds__(512, 4) void agg_kernel(
    const float* __restrict__ x, const int* __restrict__ sorted_src,
    const float4* __restrict__ sea4, const int* __restrict__ offsets,
    const float* __restrict__ emb_We, const float* __restrict__ ex_We,
    float* __restrict__ agg0, unsigned short* __restrict__ aggb) {
  __shared__ float weS[9 * DE * D];    // 36 KB: [j][k][d]
  int t = threadIdx.x;
  for (int i = t; i < 9 * DE * D; i += 512) {
    int j = i >> 10;
    int rem = i & 1023;
    weS[i] = (j == 0) ? emb_We[rem] : ex_We[(size_t)(j - 1) * 1024 + rem];
  }
  __syncthreads();
  int wv = t >> 6, lane = t & 63;

  for (int it = 0; it < 4; ++it) {
    int n = blockIdx.x * 32 + wv * 4 + it;
    int st = offsets[n], en = offsets[n + 1];
    float tk[DE];
#pragma unroll
    for (int k = 0; k < DE; ++k) tk[k] = 0.f;

    for (int base = st; base < en; base += 4) {
      int m = en - base;
      if (m > 4) m = 4;
      int idx[4], sj[4];
      float xv[4];
      float4 e0[4], e1[4], e2[4], e3[4];
#pragma unroll
      for (int j = 0; j < 4; ++j) idx[j] = base + ((j < m) ? j : 0);
#pragma unroll
      for (int j = 0; j < 4; ++j) sj[j] = sorted_src[idx[j]];
#pragma unroll
      for (int j = 0; j < 4; ++j) {
        const float4* ep = sea4 + ((size_t)idx[j] << 2);
        e0[j] = ep[0]; e1[j] = ep[1]; e2[j] = ep[2]; e3[j] = ep[3];
      }
#pragma unroll
      for (int j = 0; j < 4; ++j) xv[j] = x[(size_t)sj[j] * D + lane];
#pragma unroll
      for (int j = 0; j < 4; ++j) {
        if (j < m) {
          float xvj = xv[j];
          tk[0]  += xvj * e0[j].x; tk[1]  += xvj * e0[j].y;
          tk[2]  += xvj * e0[j].z; tk[3]  += xvj * e0[j].w;
          tk[4]  += xvj * e1[j].x; tk[5]  += xvj * e1[j].y;
          tk[6]  += xvj * e1[j].z; tk[7]  += xvj * e1[j].w;
          tk[8]  += xvj * e2[j].x; tk[9]  += xvj * e2[j].y;
          tk[10] += xvj * e2[j].z; tk[11] += xvj * e2[j].w;
          tk[12] += xvj * e3[j].x; tk[13] += xvj * e3[j].y;
          tk[14] += xvj * e3[j].z; tk[15] += xvj * e3[j].w;
        }
      }
    }
    {
      float a = 0.f;
#pragma unroll
      for (int k = 0; k < DE; ++k) a += tk[k] * weS[k * 64 + lane];
      agg0[(size_t)n * D + lane] = a;
    }
#pragma unroll
    for (int je = 0; je < NEXP; ++je) {
      const float* w = &weS[(je + 1) * 1024];
      float a = 0.f;
#pragma unroll
      for (int k = 0; k < DE; ++k) a += tk[k] * w[k * 64 + lane];
      aggb[((size_t)je * N_NODES + n) * D + lane] = f2bf(a);
    }
  }
}

// ---------------- embedding GNN (j=0, exact f32, feeds routing) ----------------

__global__ __launch_bounds__(256) void gnn0_kernel(
    const float* __restrict__ x, const float* __restrict__ agg0,
    const float* __restrict__ W1, const float* __restrict__ W2,
    const float* __restrict__ bvv, float* __restrict__ graph_emb) {
  __shared__ __align__(16) float w1s[D * D];
  __shared__ __align__(16) float w2s[D * D];
  __shared__ __align__(16) float xs[D * D];
  __shared__ __align__(16) float as2[D * D];
  int b = blockIdx.x;
  int t = threadIdx.x;
  const float4* w1src = (const float4*)W1;
  const float4* w2src = (const float4*)W2;
  const float4* xsrc  = (const float4*)(x    + (size_t)b * D * D);
  const float4* asrc  = (const float4*)(agg0 + (size_t)b * D * D);
#pragma unroll
  for (int r = 0; r < 4; ++r) {
    ((float4*)w1s)[t + r * 256] = w1src[t + r * 256];
    ((float4*)w2s)[t + r * 256] = w2src[t + r * 256];
    ((float4*)xs)[t + r * 256]  = xsrc[t + r * 256];
    ((float4*)as2)[t + r * 256] = asrc[t + r * 256];
  }
  int w = t >> 6, lane = t & 63;
  float bias = bvv[lane];
  __syncthreads();
  float pool = 0.f;
#pragma unroll
  for (int q = 0; q < 4; ++q) {
    int n0 = w * 16 + q * 4;
    float a0 = bias, a1 = bias, a2 = bias, a3 = bias;
#pragma unroll 4
    for (int c4 = 0; c4 < 16; ++c4) {
      float4 x0 = *(const float4*)&xs[(n0 + 0) * D + c4 * 4];
      float4 x1 = *(const float4*)&xs[(n0 + 1) * D + c4 * 4];
      float4 x2 = *(const float4*)&xs[(n0 + 2) * D + c4 * 4];
      float4 x3 = *(const float4*)&xs[(n0 + 3) * D + c4 * 4];
      float4 g0 = *(const float4*)&as2[(n0 + 0) * D + c4 * 4];
      float4 g1 = *(const float4*)&as2[(n0 + 1) * D + c4 * 4];
      float4 g2 = *(const float4*)&as2[(n0 + 2) * D + c4 * 4];
      float4 g3 = *(const float4*)&as2[(n0 + 3) * D + c4 * 4];
      float w10 = w1s[(c4 * 4 + 0) * D + lane];
      float w11 = w1s[(c4 * 4 + 1) * D + lane];
      float w12 = w1s[(c4 * 4 + 2) * D + lane];
      float w13 = w1s[(c4 * 4 + 3) * D + lane];
      float w20 = w2s[(c4 * 4 + 0) * D + lane];
      float w21 = w2s[(c4 * 4 + 1) * D + lane];
      float w22 = w2s[(c4 * 4 + 2) * D + lane];
      float w23 = w2s[(c4 * 4 + 3) * D + lane];
      a0 += x0.x * w10 + x0.y * w11 + x0.z * w12 + x0.w * w13
          + g0.x * w20 + g0.y * w21 + g0.z * w22 + g0.w * w23;
      a1 += x1.x * w10 + x1.y * w11 + x1.z * w12 + x1.w * w13
          + g1.x * w20 + g1.y * w21 + g1.z * w22 + g1.w * w23;
      a2 += x2.x * w10 + x2.y * w11 + x2.z * w12 + x2.w * w13
          + g2.x * w20 + g2.y * w21 + g2.z * w22 + g2.w * w23;
      a3 += x3.x * w10 + x3.y * w11 + x3.z * w12 + x3.w * w13
          + g3.x * w20 + g3.y * w21 + g3.z * w22 + g3.w * w23;
    }
    pool += fmaxf(a0, 0.f) + fmaxf(a1, 0.f) + fmaxf(a2, 0.f) + fmaxf(a3, 0.f);
  }
  __syncthreads();
  xs[w * D + lane] = pool;
  __syncthreads();
  if (w == 0) {
    float s = xs[lane] + xs[D + lane] + xs[2 * D + lane] + xs[3 * D + lane];
    graph_emb[b * D + lane] = s * (1.f / 64.f);
  }
}

// ---------------- experts (MFMA) + fused gating ----------------
// block = graph, 8 waves = 8 experts; X staged once in LDS (bf16, XOR-swizzled).
// mfma_f32_16x16x32_bf16: A row=lane&15, k=(lane>>4)*8+i ; C/D col=lane&15, row=(lane>>4)*4+reg

__global__ __launch_bounds__(512) void gnn_mfma_kernel(
    const float* __restrict__ x, const unsigned short* __restrict__ aggb,
    const unsigned short* __restrict__ wpk,
    const float* __restrict__ ex_b, const float* __restrict__ ex_Wout,
    const float* __restrict__ ex_bout,
    const float* __restrict__ graph_emb, const float* __restrict__ Wg,
    const float* __restrict__ bg, float* __restrict__ out) {
  __shared__ __align__(16) short xls[4096];   // 64x64 bf16, swizzled
  __shared__ float pg[NEXP];
  __shared__ float lg[NEXP];
  int g = blockIdx.x;
  int t = threadIdx.x;
  {
    const float4* xp = (const float4*)(x + (size_t)g * 4096 + (size_t)t * 8);
    float4 va = xp[0], vb = xp[1];
    short8v pk;
    pk[0] = (short)f2bf(va.x); pk[1] = (short)f2bf(va.y);
    pk[2] = (short)f2bf(va.z); pk[3] = (short)f2bf(va.w);
    pk[4] = (short)f2bf(vb.x); pk[5] = (short)f2bf(vb.y);
    pk[6] = (short)f2bf(vb.z); pk[7] = (short)f2bf(vb.w);
    int row = t >> 3, slot = t & 7;
    *(short8v*)((char*)xls + (((row << 3) + (slot ^ (row & 7))) << 4)) = pk;
  }
  __syncthreads();

  int je = t >> 6;
  int lane = t & 63;
  int r = lane & 15, q = lane >> 4;

  const short* Ab = (const short*)(aggb + ((size_t)je * N_NODES + (size_t)g * D) * D);
  const short* B1 = (const short*)(wpk + (size_t)je * 2 * 4096);
  const short* B2 = B1 + 4096;

  floatx4 acc[4][4];
#pragma unroll
  for (int i = 0; i < 4; ++i)
#pragma unroll
    for (int j = 0; j < 4; ++j) acc[i][j] = (floatx4){0.f, 0.f, 0.f, 0.f};

  // phase 1: X(LDS) @ W1(global)
#pragma unroll
  for (int kk = 0; kk < 2; ++kk) {
    int ko = kk * 32 + q * 8;
    short8v af[4], bf[4];
#pragma unroll
    for (int rt = 0; rt < 4; ++rt) {
      int row = rt * 16 + r;
      int slot = kk * 4 + q;
      af[rt] = *(const short8v*)((char*)xls + (((row << 3) + (slot ^ (row & 7))) << 4));
    }
#pragma unroll
    for (int ct = 0; ct < 4; ++ct) bf[ct] = *(const short8v*)(B1 + (ct * 16 + r) * D + ko);
#pragma unroll
    for (int rt = 0; rt < 4; ++rt)
#pragma unroll
      for (int ct = 0; ct < 4; ++ct)
        acc[rt][ct] = __builtin_amdgcn_mfma_f32_16x16x32_bf16(af[rt], bf[ct], acc[rt][ct], 0, 0, 0);
  }
  // phase 2: AGG(global) @ W2(global)
#pragma unroll
  for (int kk = 0; kk < 2; ++kk) {
    int ko = kk * 32 + q * 8;
    short8v af[4], bf[4];
#pragma unroll
    for (int rt = 0; rt < 4; ++rt) af[rt] = *(const short8v*)(Ab + (rt * 16 + r) * D + ko);
#pragma unroll
    for (int ct = 0; ct < 4; ++ct) bf[ct] = *(const short8v*)(B2 + (ct * 16 + r) * D + ko);
#pragma unroll
    for (int rt = 0; rt < 4; ++rt)
#pragma unroll
      for (int ct = 0; ct < 4; ++ct)
        acc[rt][ct] = __builtin_amdgcn_mfma_f32_16x16x32_bf16(af[rt], bf[ct], acc[rt][ct], 0, 0, 0);
  }

  // epilogue: relu(+bias), pool over 64 rows, dot with Wout, mean, +bout -> LDS
  float o = 0.f;
#pragma unroll
  for (int ct = 0; ct < 4; ++ct) {
    float bcol = ex_b[je * D + ct * 16 + r];
    float s = 0.f;
#pragma unroll
    for (int rt = 0; rt < 4; ++rt)
#pragma unroll
      for (int rg = 0; rg < 4; ++rg) s += fmaxf(acc[rt][ct][rg] + bcol, 0.f);
    s += __shfl_xor(s, 16);
    s += __shfl_xor(s, 32);
    o += s * ex_Wout[je * D + ct * 16 + r];
  }
#pragma unroll
  for (int off = 8; off >= 1; off >>= 1) o += __shfl_xor(o, off);
  if (lane == 0) pg[je] = o * (1.f / 64.f) + ex_bout[je];
  __syncthreads();

  // fused gating (exact f32): reuse xls as float scratch for graph_emb row
  float* es = (float*)xls;
  if (t < 64) es[t] = graph_emb[g * D + t];
  __syncthreads();
  if (t < NEXP) {
    float v = bg[t];
    for (int d = 0; d < D; ++d) v += es[d] * Wg[d * NEXP + t];
    lg[t] = v;
  }
  __syncthreads();
  if (t < NEXP) {
    float l[NEXP];
    float mx = -1e30f;
#pragma unroll
    for (int e = 0; e < NEXP; ++e) { l[e] = lg[e]; mx = fmaxf(mx, l[e]); }
    float p[NEXP];
    float sum = 0.f;
#pragma unroll
    for (int e = 0; e < NEXP; ++e) { p[e] = expf(l[e] - mx); sum += p[e]; }
    float inv = 1.f / sum;
#pragma unroll
    for (int e = 0; e < NEXP; ++e) p[e] *= inv;
    out[NB + g * NEXP + t] = p[t];
    if (t == 0) {
      int i1 = -1; float v1 = -1e30f;
#pragma unroll
      for (int e = 0; e < NEXP; ++e) if (p[e] > v1) { v1 = p[e]; i1 = e; }
      int i2 = -1; float v2 = -1e30f;
#pragma unroll
      for (int e = 0; e < NEXP; ++e) if (e != i1 && p[e] > v2) { v2 = p[e]; i2 = e; }
      float rr = expf(v2 - v1);
      float n1 = 1.f / (1.f + rr);
      float n2 = rr / (1.f + rr);
      out[g] = n1 * pg[i1] + n2 * pg[i2];
    }
  }
}

// ---------------- launch ----------------

extern "C" void kernel_launch(void* const* d_in, const int* in_sizes, int n_in,
                              void* d_out, int out_size, void* d_ws, size_t ws_size,
                              hipStream_t stream) {
  const float* x         = (const float*)d_in[0];
  const float* edge_attr = (const float*)d_in[1];
  const float* emb_We    = (const float*)d_in[2];
  const float* emb_W1    = (const float*)d_in[3];
  const float* emb_W2    = (const float*)d_in[4];
  const float* emb_b     = (const float*)d_in[5];
  const float* Wg        = (const float*)d_in[6];
  const float* bg        = (const float*)d_in[7];
  const float* ex_We     = (const float*)d_in[8];
  const float* ex_W1     = (const float*)d_in[9];
  const float* ex_W2     = (const float*)d_in[10];
  const float* ex_b      = (const float*)d_in[11];
  const float* ex_Wout   = (const float*)d_in[12];
  const float* ex_bout   = (const float*)d_in[13];
  const int* edge_src    = (const int*)d_in[14];
  const int* edge_dst    = (const int*)d_in[15];

  char* p = (char*)d_ws;
  auto alloc = [&](size_t bytes) {
    char* q = p;
    p += (bytes + 255) & ~(size_t)255;
    return q;
  };
  int*   counts     = (int*)alloc((size_t)N_NODES * 4);
  int*   offsets    = (int*)alloc((size_t)(N_NODES + 1) * 4);
  int*   cursor     = (int*)alloc((size_t)N_NODES * 4);
  int*   bsums      = (int*)alloc(128 * 4);
  int*   sorted_src = (int*)alloc((size_t)N_EDGES * 4);
  float* sorted_ea  = (float*)alloc((size_t)N_EDGES * DE * 4);
  float* agg0       = (float*)alloc((size_t)N_NODES * D * 4);
  unsigned short* aggb = (unsigned short*)alloc((size_t)NEXP * N_NODES * D * 2);
  unsigned short* wpk  = (unsigned short*)alloc((size_t)NEXP * 2 * D * D * 2);
  float* graph_emb  = (float*)alloc((size_t)NB * D * 4);

  hipMemsetAsync(counts, 0, (size_t)N_NODES * 4, stream);
  hist_kernel<<<N_EDGES / 256, 256, 0, stream>>>(edge_dst, counts);
  scan1_kernel<<<N_NODES / 256, 256, 0, stream>>>(counts, offsets, bsums);
  scan2_kernel<<<1, 128, 0, stream>>>(bsums);
  scan3_kernel<<<N_NODES / 256, 256, 0, stream>>>(offsets, bsums, cursor);
  scatter_kernel<<<N_EDGES / 256, 256, 0, stream>>>(edge_dst, edge_src,
                                                    (const float4*)edge_attr, cursor,
                                                    sorted_src, (float4*)sorted_ea,
                                                    ex_W1, ex_W2, wpk);
  agg_kernel<<<N_NODES / 32, 512, 0, stream>>>(x, sorted_src, (const float4*)sorted_ea,
                                               offsets, emb_We, ex_We, agg0, aggb);
  gnn0_kernel<<<NB, 256, 0, stream>>>(x, agg0, emb_W1, emb_W2, emb_b, graph_emb);
  gnn_mfma_kernel<<<NB, 512, 0, stream>>>(x, aggb, wpk, ex_b, ex_Wout, ex_bout,
                                          graph_emb, Wg, bg, (float*)d_out);
}

// Round 6
// 406.506 us; speedup vs baseline: 1.0488x; 1.0488x over previous
//
#include <hip/hip_runtime.h>

#define N_NODES 32768
#define N_EDGES 262144
#define NB      512
#define D       64
#define DE      16
#define NEXP    8

typedef __attribute__((ext_vector_type(8))) short  short8v;
typedef __attribute__((ext_vector_type(4))) float  floatx4;

static __device__ __forceinline__ unsigned short f2bf(float f) {
  unsigned int u = __float_as_uint(f);
  u += 0x7FFFu + ((u >> 16) & 1u);
  return (unsigned short)(u >> 16);
}

// ---------------- sort edges by dst ----------------

__global__ void hist_kernel(const int* __restrict__ dst, int* __restrict__ counts) {
  int i = blockIdx.x * blockDim.x + threadIdx.x;
  if (i < N_EDGES) atomicAdd(&counts[dst[i]], 1);
}

__global__ void scan1_kernel(const int* __restrict__ counts, int* __restrict__ offsets,
                             int* __restrict__ bsums) {
  __shared__ int sm[256];
  int t = threadIdx.x, i = blockIdx.x * 256 + t;
  int v = counts[i];
  sm[t] = v;
  __syncthreads();
  for (int off = 1; off < 256; off <<= 1) {
    int u = (t >= off) ? sm[t - off] : 0;
    __syncthreads();
    sm[t] += u;
    __syncthreads();
  }
  offsets[i] = sm[t] - v;              // in-block exclusive
  if (t == 255) bsums[blockIdx.x] = sm[255];
}

__global__ void scan2_kernel(int* __restrict__ bsums) {
  __shared__ int sm[128];
  int t = threadIdx.x;
  int v = bsums[t];
  sm[t] = v;
  __syncthreads();
  for (int off = 1; off < 128; off <<= 1) {
    int u = (t >= off) ? sm[t - off] : 0;
    __syncthreads();
    sm[t] += u;
    __syncthreads();
  }
  bsums[t] = sm[t] - v;                // exclusive block offsets
}

__global__ void scan3_kernel(int* __restrict__ offsets, const int* __restrict__ bsums,
                             int* __restrict__ cursor) {
  int i = blockIdx.x * 256 + threadIdx.x;
  int v = offsets[i] + bsums[blockIdx.x];
  offsets[i] = v;
  cursor[i]  = v;
  if (i == 0) offsets[N_NODES] = N_EDGES;
}

// scatter sorted payload (+ fused weight pack in spare thread range)
__global__ void scatter_kernel(const int* __restrict__ dst, const int* __restrict__ src,
                               const float4* __restrict__ ea4, int* __restrict__ cursor,
                               int* __restrict__ sorted_src, float4* __restrict__ sea4,
                               const float* __restrict__ ex_W1, const float* __restrict__ ex_W2,
                               unsigned short* __restrict__ wpk) {
  int i = blockIdx.x * blockDim.x + threadIdx.x;
  if (i < N_EDGES) {
    int p = atomicAdd(&cursor[dst[i]], 1);
    sorted_src[p] = src[i];
    float4 a = ea4[(size_t)i * 4 + 0];
    float4 b = ea4[(size_t)i * 4 + 1];
    float4 c = ea4[(size_t)i * 4 + 2];
    float4 d = ea4[(size_t)i * 4 + 3];
    sea4[(size_t)p * 4 + 0] = a;
    sea4[(size_t)p * 4 + 1] = b;
    sea4[(size_t)p * 4 + 2] = c;
    sea4[(size_t)p * 4 + 3] = d;
  }
  if (i < NEXP * 2 * D * D) {          // wpk[je][mat][col][k] = W_mat_je[k][col]
    int je  = i >> 13;
    int rem = i & 8191;
    int mat = rem >> 12;
    int cd  = rem & 4095;
    int col = cd >> 6, k = cd & 63;
    const float* W = mat ? ex_W2 : ex_W1;
    wpk[i] = f2bf(W[je * 4096 + k * 64 + col]);
  }
}

// ---------------- tkern: gather-only. wave = node, lane = d. ----------------
// T[n][d][k] = sum_{e: dst=n} x[src[e],d] * ea[e,k]   (per-lane 64B contiguous store)

__global__ __launch_bounds__(256) void tkern(
    const float* __restrict__ x, const int* __restrict__ sorted_src,
    const float4* __restrict__ sea4, const int* __restrict__ offsets,
    float* __restrict__ T) {
  int lane = threadIdx.x & 63;
  int n = blockIdx.x * 4 + (threadIdx.x >> 6);
  int st = offsets[n], en = offsets[n + 1];
  float tk[DE];
#pragma unroll
  for (int k = 0; k < DE; ++k) tk[k] = 0.f;

  for (int base = st; base < en; base += 2) {
    int i1 = (base + 1 < en) ? base + 1 : base;
    int sa = sorted_src[base];
    int sb = sorted_src[i1];
    const float4* pa = sea4 + ((size_t)base << 2);
    const float4* pb = sea4 + ((size_t)i1 << 2);
    float4 a0 = pa[0], a1 = pa[1], a2 = pa[2], a3 = pa[3];
    float4 b0 = pb[0], b1 = pb[1], b2 = pb[2], b3 = pb[3];
    float xa = x[(size_t)sa * D + lane];
    float xb = x[(size_t)sb * D + lane];
    tk[0]  += xa * a0.x; tk[1]  += xa * a0.y; tk[2]  += xa * a0.z; tk[3]  += xa * a0.w;
    tk[4]  += xa * a1.x; tk[5]  += xa * a1.y; tk[6]  += xa * a1.z; tk[7]  += xa * a1.w;
    tk[8]  += xa * a2.x; tk[9]  += xa * a2.y; tk[10] += xa * a2.z; tk[11] += xa * a2.w;
    tk[12] += xa * a3.x; tk[13] += xa * a3.y; tk[14] += xa * a3.z; tk[15] += xa * a3.w;
    if (base + 1 < en) {
      tk[0]  += xb * b0.x; tk[1]  += xb * b0.y; tk[2]  += xb * b0.z; tk[3]  += xb * b0.w;
      tk[4]  += xb * b1.x; tk[5]  += xb * b1.y; tk[6]  += xb * b1.z; tk[7]  += xb * b1.w;
      tk[8]  += xb * b2.x; tk[9]  += xb * b2.y; tk[10] += xb * b2.z; tk[11] += xb * b2.w;
      tk[12] += xb * b3.x; tk[13] += xb * b3.y; tk[14] += xb * b3.z; tk[15] += xb * b3.w;
    }
  }
  floatx4* tp = (floatx4*)(T + (size_t)n * (D * DE) + (size_t)lane * DE);
#pragma unroll
  for (int c = 0; c < 4; ++c) {
    floatx4 v = {tk[4 * c + 0], tk[4 * c + 1], tk[4 * c + 2], tk[4 * c + 3]};
    tp[c] = v;
  }
}

// ---------------- contract: agg_j[n,d] = sum_k T[n,d,k] * We_j[k,d] ----------------
// block = (node-chunk, je); We column held in 16 VGPRs, T streamed coalesced. Zero LDS.

__global__ __launch_bounds__(256) void contract_kernel(
    const float* __restrict__ T, const float* __restrict__ emb_We,
    const float* __restrict__ ex_We, float* __restrict__ agg0,
    unsigned short* __restrict__ aggb) {
  int je = blockIdx.y;                  // 0 = embedding, 1..8 = experts
  int lane = threadIdx.x & 63;
  int w = threadIdx.x >> 6;
  const float* We = (je == 0) ? emb_We : ex_We + (size_t)(je - 1) * DE * D;
  float wr[DE];
#pragma unroll
  for (int k = 0; k < DE; ++k) wr[k] = We[k * D + lane];

  int n0 = blockIdx.x * 64 + w * 16;    // 16 nodes per wave
  for (int i = 0; i < 16; i += 2) {
    int nA = n0 + i, nB = n0 + i + 1;
    const floatx4* ta = (const floatx4*)(T + (size_t)nA * (D * DE) + (size_t)lane * DE);
    const floatx4* tb = (const floatx4*)(T + (size_t)nB * (D * DE) + (size_t)lane * DE);
    floatx4 a0 = ta[0], a1 = ta[1], a2 = ta[2], a3 = ta[3];
    floatx4 b0 = tb[0], b1 = tb[1], b2 = tb[2], b3 = tb[3];
    float sA = a0[0] * wr[0]  + a0[1] * wr[1]  + a0[2] * wr[2]  + a0[3] * wr[3]
             + a1[0] * wr[4]  + a1[1] * wr[5]  + a1[2] * wr[6]  + a1[3] * wr[7]
             + a2[0] * wr[8]  + a2[1] * wr[9]  + a2[2] * wr[10] + a2[3] * wr[11]
             + a3[0] * wr[12] + a3[1] * wr[13] + a3[2] * wr[14] + a3[3] * wr[15];
    float sB = b0[0] * wr[0]  + b0[1] * wr[1]  + b0[2] * wr[2]  + b0[3] * wr[3]
             + b1[0] * wr[4]  + b1[1] * wr[5]  + b1[2] * wr[6]  + b1[3] * wr[7]
             + b2[0] * wr[8]  + b2[1] * wr[9]  + b2[2] * wr[10] + b2[3] * wr[11]
             + b3[0] * wr[12] + b3[1] * wr[13] + b3[2] * wr[14] + b3[3] * wr[15];
    if (je == 0) {
      agg0[(size_t)nA * D + lane] = sA;
      agg0[(size_t)nB * D + lane] = sB;
    } else {
      aggb[((size_t)(je - 1) * N_NODES + nA) * D + lane] = f2bf(sA);
      aggb[((size_t)(je - 1) * N_NODES + nB) * D + lane] = f2bf(sB);
    }
  }
}

// ---------------- embedding GNN (j=0, exact f32, feeds routing) ----------------

__global__ __launch_bounds__(256) void gnn0_kernel(
    const float* __restrict__ x, const float* __restrict__ agg0,
    const float* __restrict__ W1, const float* __restrict__ W2,
    const float* __restrict__ bvv, float* __restrict__ graph_emb) {
  __shared__ __align__(16) float w1s[D * D];
  __shared__ __align__(16) float w2s[D * D];
  __shared__ __align__(16) float xs[D * D];
  __shared__ __align__(16) float as2[D * D];
  int b = blockIdx.x;
  int t = threadIdx.x;
  const float4* w1src = (const float4*)W1;
  const float4* w2src = (const float4*)W2;
  const float4* xsrc  = (const float4*)(x    + (size_t)b * D * D);
  const float4* asrc  = (const float4*)(agg0 + (size_t)b * D * D);
#pragma unroll
  for (int r = 0; r < 4; ++r) {
    ((float4*)w1s)[t + r * 256] = w1src[t + r * 256];
    ((float4*)w2s)[t + r * 256] = w2src[t + r * 256];
    ((float4*)xs)[t + r * 256]  = xsrc[t + r * 256];
    ((float4*)as2)[t + r * 256] = asrc[t + r * 256];
  }
  int w = t >> 6, lane = t & 63;
  float bias = bvv[lane];
  __syncthreads();
  float pool = 0.f;
#pragma unroll
  for (int q = 0; q < 4; ++q) {
    int n0 = w * 16 + q * 4;
    float a0 = bias, a1 = bias, a2 = bias, a3 = bias;
#pragma unroll 4
    for (int c4 = 0; c4 < 16; ++c4) {
      float4 x0 = *(const float4*)&xs[(n0 + 0) * D + c4 * 4];
      float4 x1 = *(const float4*)&xs[(n0 + 1) * D + c4 * 4];
      float4 x2 = *(const float4*)&xs[(n0 + 2) * D + c4 * 4];
      float4 x3 = *(const float4*)&xs[(n0 + 3) * D + c4 * 4];
      float4 g0 = *(const float4*)&as2[(n0 + 0) * D + c4 * 4];
      float4 g1 = *(const float4*)&as2[(n0 + 1) * D + c4 * 4];
      float4 g2 = *(const float4*)&as2[(n0 + 2) * D + c4 * 4];
      float4 g3 = *(const float4*)&as2[(n0 + 3) * D + c4 * 4];
      float w10 = w1s[(c4 * 4 + 0) * D + lane];
      float w11 = w1s[(c4 * 4 + 1) * D + lane];
      float w12 = w1s[(c4 * 4 + 2) * D + lane];
      float w13 = w1s[(c4 * 4 + 3) * D + lane];
      float w20 = w2s[(c4 * 4 + 0) * D + lane];
      float w21 = w2s[(c4 * 4 + 1) * D + lane];
      float w22 = w2s[(c4 * 4 + 2) * D + lane];
      float w23 = w2s[(c4 * 4 + 3) * D + lane];
      a0 += x0.x * w10 + x0.y * w11 + x0.z * w12 + x0.w * w13
          + g0.x * w20 + g0.y * w21 + g0.z * w22 + g0.w * w23;
      a1 += x1.x * w10 + x1.y * w11 + x1.z * w12 + x1.w * w13
          + g1.x * w20 + g1.y * w21 + g1.z * w22 + g1.w * w23;
      a2 += x2.x * w10 + x2.y * w11 + x2.z * w12 + x2.w * w13
          + g2.x * w20 + g2.y * w21 + g2.z * w22 + g2.w * w23;
      a3 += x3.x * w10 + x3.y * w11 + x3.z * w12 + x3.w * w13
          + g3.x * w20 + g3.y * w21 + g3.z * w22 + g3.w * w23;
    }
    pool += fmaxf(a0, 0.f) + fmaxf(a1, 0.f) + fmaxf(a2, 0.f) + fmaxf(a3, 0.f);
  }
  __syncthreads();
  xs[w * D + lane] = pool;
  __syncthreads();
  if (w == 0) {
    float s = xs[lane] + xs[D + lane] + xs[2 * D + lane] + xs[3 * D + lane];
    graph_emb[b * D + lane] = s * (1.f / 64.f);
  }
}

// ---------------- experts (MFMA) + fused gating ----------------
// block = graph, 8 waves = 8 experts; X staged once in LDS (bf16, XOR-swizzled).
// mfma_f32_16x16x32_bf16: A row=lane&15, k=(lane>>4)*8+i ; C/D col=lane&15, row=(lane>>4)*4+reg

__global__ __launch_bounds__(512) void gnn_mfma_kernel(
    const float* __restrict__ x, const unsigned short* __restrict__ aggb,
    const unsigned short* __restrict__ wpk,
    const float* __restrict__ ex_b, const float* __restrict__ ex_Wout,
    const float* __restrict__ ex_bout,
    const float* __restrict__ graph_emb, const float* __restrict__ Wg,
    const float* __restrict__ bg, float* __restrict__ out) {
  __shared__ __align__(16) short xls[4096];   // 64x64 bf16, swizzled
  __shared__ float pg[NEXP];
  __shared__ float lg[NEXP];
  int g = blockIdx.x;
  int t = threadIdx.x;
  {
    const float4* xp = (const float4*)(x + (size_t)g * 4096 + (size_t)t * 8);
    float4 va = xp[0], vb = xp[1];
    short8v pk;
    pk[0] = (short)f2bf(va.x); pk[1] = (short)f2bf(va.y);
    pk[2] = (short)f2bf(va.z); pk[3] = (short)f2bf(va.w);
    pk[4] = (short)f2bf(vb.x); pk[5] = (short)f2bf(vb.y);
    pk[6] = (short)f2bf(vb.z); pk[7] = (short)f2bf(vb.w);
    int row = t >> 3, slot = t & 7;
    *(short8v*)((char*)xls + (((row << 3) + (slot ^ (row & 7))) << 4)) = pk;
  }
  __syncthreads();

  int je = t >> 6;
  int lane = t & 63;
  int r = lane & 15, q = lane >> 4;

  const short* Ab = (const short*)(aggb + ((size_t)je * N_NODES + (size_t)g * D) * D);
  const short* B1 = (const short*)(wpk + (size_t)je * 2 * 4096);
  const short* B2 = B1 + 4096;

  floatx4 acc[4][4];
#pragma unroll
  for (int i = 0; i < 4; ++i)
#pragma unroll
    for (int j = 0; j < 4; ++j) acc[i][j] = (floatx4){0.f, 0.f, 0.f, 0.f};

  // phase 1: X(LDS) @ W1(global)
#pragma unroll
  for (int kk = 0; kk < 2; ++kk) {
    int ko = kk * 32 + q * 8;
    short8v af[4], bf[4];
#pragma unroll
    for (int rt = 0; rt < 4; ++rt) {
      int row = rt * 16 + r;
      int slot = kk * 4 + q;
      af[rt] = *(const short8v*)((char*)xls + (((row << 3) + (slot ^ (row & 7))) << 4));
    }
#pragma unroll
    for (int ct = 0; ct < 4; ++ct) bf[ct] = *(const short8v*)(B1 + (ct * 16 + r) * D + ko);
#pragma unroll
    for (int rt = 0; rt < 4; ++rt)
#pragma unroll
      for (int ct = 0; ct < 4; ++ct)
        acc[rt][ct] = __builtin_amdgcn_mfma_f32_16x16x32_bf16(af[rt], bf[ct], acc[rt][ct], 0, 0, 0);
  }
  // phase 2: AGG(global) @ W2(global)
#pragma unroll
  for (int kk = 0; kk < 2; ++kk) {
    int ko = kk * 32 + q * 8;
    short8v af[4], bf[4];
#pragma unroll
    for (int rt = 0; rt < 4; ++rt) af[rt] = *(const short8v*)(Ab + (rt * 16 + r) * D + ko);
#pragma unroll
    for (int ct = 0; ct < 4; ++ct) bf[ct] = *(const short8v*)(B2 + (ct * 16 + r) * D + ko);
#pragma unroll
    for (int rt = 0; rt < 4; ++rt)
#pragma unroll
      for (int ct = 0; ct < 4; ++ct)
        acc[rt][ct] = __builtin_amdgcn_mfma_f32_16x16x32_bf16(af[rt], bf[ct], acc[rt][ct], 0, 0, 0);
  }

  // epilogue: relu(+bias), pool over 64 rows, dot with Wout, mean, +bout -> LDS
  float o = 0.f;
#pragma unroll
  for (int ct = 0; ct < 4; ++ct) {
    float bcol = ex_b[je * D + ct * 16 + r];
    float s = 0.f;
#pragma unroll
    for (int rt = 0; rt < 4; ++rt)
#pragma unroll
      for (int rg = 0; rg < 4; ++rg) s += fmaxf(acc[rt][ct][rg] + bcol, 0.f);
    s += __shfl_xor(s, 16);
    s += __shfl_xor(s, 32);
    o += s * ex_Wout[je * D + ct * 16 + r];
  }
#pragma unroll
  for (int off = 8; off >= 1; off >>= 1) o += __shfl_xor(o, off);
  if (lane == 0) pg[je] = o * (1.f / 64.f) + ex_bout[je];
  __syncthreads();

  // fused gating (exact f32): reuse xls as float scratch for graph_emb row
  float* es = (float*)xls;
  if (t < 64) es[t] = graph_emb[g * D + t];
  __syncthreads();
  if (t < NEXP) {
    float v = bg[t];
    for (int d = 0; d < D; ++d) v += es[d] * Wg[d * NEXP + t];
    lg[t] = v;
  }
  __syncthreads();
  if (t < NEXP) {
    float l[NEXP];
    float mx = -1e30f;
#pragma unroll
    for (int e = 0; e < NEXP; ++e) { l[e] = lg[e]; mx = fmaxf(mx, l[e]); }
    float p[NEXP];
    float sum = 0.f;
#pragma unroll
    for (int e = 0; e < NEXP; ++e) { p[e] = expf(l[e] - mx); sum += p[e]; }
    float inv = 1.f / sum;
#pragma unroll
    for (int e = 0; e < NEXP; ++e) p[e] *= inv;
    out[NB + g * NEXP + t] = p[t];
    if (t == 0) {
      int i1 = -1; float v1 = -1e30f;
#pragma unroll
      for (int e = 0; e < NEXP; ++e) if (p[e] > v1) { v1 = p[e]; i1 = e; }
      int i2 = -1; float v2 = -1e30f;
#pragma unroll
      for (int e = 0; e < NEXP; ++e) if (e != i1 && p[e] > v2) { v2 = p[e]; i2 = e; }
      float rr = expf(v2 - v1);
      float n1 = 1.f / (1.f + rr);
      float n2 = rr / (1.f + rr);
      out[g] = n1 * pg[i1] + n2 * pg[i2];
    }
  }
}

// ---------------- launch ----------------

extern "C" void kernel_launch(void* const* d_in, const int* in_sizes, int n_in,
                              void* d_out, int out_size, void* d_ws, size_t ws_size,
                              hipStream_t stream) {
  const float* x         = (const float*)d_in[0];
  const float* edge_attr = (const float*)d_in[1];
  const float* emb_We    = (const float*)d_in[2];
  const float* emb_W1    = (const float*)d_in[3];
  const float* emb_W2    = (const float*)d_in[4];
  const float* emb_b     = (const float*)d_in[5];
  const float* Wg        = (const float*)d_in[6];
  const float* bg        = (const float*)d_in[7];
  const float* ex_We     = (const float*)d_in[8];
  const float* ex_W1     = (const float*)d_in[9];
  const float* ex_W2     = (const float*)d_in[10];
  const float* ex_b      = (const float*)d_in[11];
  const float* ex_Wout   = (const float*)d_in[12];
  const float* ex_bout   = (const float*)d_in[13];
  const int* edge_src    = (const int*)d_in[14];
  const int* edge_dst    = (const int*)d_in[15];

  char* p = (char*)d_ws;
  auto alloc = [&](size_t bytes) {
    char* q = p;
    p += (bytes + 255) & ~(size_t)255;
    return q;
  };
  int*   counts     = (int*)alloc((size_t)N_NODES * 4);
  int*   offsets    = (int*)alloc((size_t)(N_NODES + 1) * 4);
  int*   cursor     = (int*)alloc((size_t)N_NODES * 4);
  int*   bsums      = (int*)alloc(128 * 4);
  int*   sorted_src = (int*)alloc((size_t)N_EDGES * 4);
  float* sorted_ea  = (float*)alloc((size_t)N_EDGES * DE * 4);
  float* Tbuf       = (float*)alloc((size_t)N_NODES * D * DE * 4);   // 8 MB
  float* agg0       = (float*)alloc((size_t)N_NODES * D * 4);
  unsigned short* aggb = (unsigned short*)alloc((size_t)NEXP * N_NODES * D * 2);
  unsigned short* wpk  = (unsigned short*)alloc((size_t)NEXP * 2 * D * D * 2);
  float* graph_emb  = (float*)alloc((size_t)NB * D * 4);

  hipMemsetAsync(counts, 0, (size_t)N_NODES * 4, stream);
  hist_kernel<<<N_EDGES / 256, 256, 0, stream>>>(edge_dst, counts);
  scan1_kernel<<<N_NODES / 256, 256, 0, stream>>>(counts, offsets, bsums);
  scan2_kernel<<<1, 128, 0, stream>>>(bsums);
  scan3_kernel<<<N_NODES / 256, 256, 0, stream>>>(offsets, bsums, cursor);
  scatter_kernel<<<N_EDGES / 256, 256, 0, stream>>>(edge_dst, edge_src,
                                                    (const float4*)edge_attr, cursor,
                                                    sorted_src, (float4*)sorted_ea,
                                                    ex_W1, ex_W2, wpk);
  tkern<<<N_NODES / 4, 256, 0, stream>>>(x, sorted_src, (const float4*)sorted_ea,
                                         offsets, Tbuf);
  dim3 cgrid(N_NODES / 64, 9);
  contract_kernel<<<cgrid, 256, 0, stream>>>(Tbuf, emb_We, ex_We, agg0, aggb);
  gnn0_kernel<<<NB, 256, 0, stream>>>(x, agg0, emb_W1, emb_W2, emb_b, graph_emb);
  gnn_mfma_kernel<<<NB, 512, 0, stream>>>(x, aggb, wpk, ex_b, ex_Wout, ex_bout,
                                          graph_emb, Wg, bg, (float*)d_out);
}

// Round 7
// 247.515 us; speedup vs baseline: 1.7226x; 1.6423x over previous
//
#include <hip/hip_runtime.h>

#define N_NODES 32768
#define N_EDGES 262144
#define NB      512
#define D       64
#define DE      16
#define NEXP    8

typedef __attribute__((ext_vector_type(8))) short  short8v;
typedef __attribute__((ext_vector_type(4))) float  floatx4;

static __device__ __forceinline__ unsigned short f2bf(float f) {
  unsigned int u = __float_as_uint(f);
  u += 0x7FFFu + ((u >> 16) & 1u);
  return (unsigned short)(u >> 16);
}

// ---------------- sort edges by dst ----------------

__global__ void hist_kernel(const int* __restrict__ dst, int* __restrict__ counts) {
  int i = blockIdx.x * blockDim.x + threadIdx.x;
  if (i < N_EDGES) atomicAdd(&counts[dst[i]], 1);
}

__global__ void scan1_kernel(const int* __restrict__ counts, int* __restrict__ offsets,
                             int* __restrict__ bsums) {
  __shared__ int sm[256];
  int t = threadIdx.x, i = blockIdx.x * 256 + t;
  int v = counts[i];
  sm[t] = v;
  __syncthreads();
  for (int off = 1; off < 256; off <<= 1) {
    int u = (t >= off) ? sm[t - off] : 0;
    __syncthreads();
    sm[t] += u;
    __syncthreads();
  }
  offsets[i] = sm[t] - v;              // in-block exclusive
  if (t == 255) bsums[blockIdx.x] = sm[255];
}

__global__ void scan2_kernel(int* __restrict__ bsums) {
  __shared__ int sm[128];
  int t = threadIdx.x;
  int v = bsums[t];
  sm[t] = v;
  __syncthreads();
  for (int off = 1; off < 128; off <<= 1) {
    int u = (t >= off) ? sm[t - off] : 0;
    __syncthreads();
    sm[t] += u;
    __syncthreads();
  }
  bsums[t] = sm[t] - v;                // exclusive block offsets
}

__global__ void scan3_kernel(int* __restrict__ offsets, const int* __restrict__ bsums,
                             int* __restrict__ cursor) {
  int i = blockIdx.x * 256 + threadIdx.x;
  int v = offsets[i] + bsums[blockIdx.x];
  offsets[i] = v;
  cursor[i]  = v;
  if (i == 0) offsets[N_NODES] = N_EDGES;
}

// scatter sorted payload (+ fused weight pack in spare thread range)
__global__ void scatter_kernel(const int* __restrict__ dst, const int* __restrict__ src,
                               const float4* __restrict__ ea4, int* __restrict__ cursor,
                               int* __restrict__ sorted_src, float4* __restrict__ sea4,
                               const float* __restrict__ ex_W1, const float* __restrict__ ex_W2,
                               unsigned short* __restrict__ wpk) {
  int i = blockIdx.x * blockDim.x + threadIdx.x;
  if (i < N_EDGES) {
    int p = atomicAdd(&cursor[dst[i]], 1);
    sorted_src[p] = src[i];
    float4 a = ea4[(size_t)i * 4 + 0];
    float4 b = ea4[(size_t)i * 4 + 1];
    float4 c = ea4[(size_t)i * 4 + 2];
    float4 d = ea4[(size_t)i * 4 + 3];
    sea4[(size_t)p * 4 + 0] = a;
    sea4[(size_t)p * 4 + 1] = b;
    sea4[(size_t)p * 4 + 2] = c;
    sea4[(size_t)p * 4 + 3] = d;
  }
  if (i < NEXP * 2 * D * D) {          // wpk[je][mat][col][k] = W_mat_je[k][col]
    int je  = i >> 13;
    int rem = i & 8191;
    int mat = rem >> 12;
    int cd  = rem & 4095;
    int col = cd >> 6, k = cd & 63;
    const float* W = mat ? ex_W2 : ex_W1;
    wpk[i] = f2bf(W[je * 4096 + k * 64 + col]);
  }
}

// ---------------- tkern: gather + exact agg0 + packed-bf16 T ----------------
// wave = node, lane = d. tk[k] = sum_e x[src[e],d]*ea[e,k] (f32).
// agg0[n,d] = sum_k tk[k]*emb_We[k,d]  (exact, feeds routing)
// T32[n][j][d] = pack(bf16(tk[2j]), bf16(tk[2j+1]))  -> 64 MB, coalesced dwords

__global__ __launch_bounds__(256) void tkern(
    const float* __restrict__ x, const int* __restrict__ sorted_src,
    const float4* __restrict__ sea4, const int* __restrict__ offsets,
    const float* __restrict__ emb_We, float* __restrict__ agg0,
    unsigned int* __restrict__ Tp) {
  int lane = threadIdx.x & 63;
  int n = blockIdx.x * 4 + (threadIdx.x >> 6);
  int st = offsets[n], en = offsets[n + 1];
  float ew[DE];
#pragma unroll
  for (int k = 0; k < DE; ++k) ew[k] = emb_We[k * D + lane];
  float tk[DE];
#pragma unroll
  for (int k = 0; k < DE; ++k) tk[k] = 0.f;

  for (int base = st; base < en; base += 2) {
    int i1 = (base + 1 < en) ? base + 1 : base;
    int sa = sorted_src[base];
    int sb = sorted_src[i1];
    const float4* pa = sea4 + ((size_t)base << 2);
    const float4* pb = sea4 + ((size_t)i1 << 2);
    float4 a0 = pa[0], a1 = pa[1], a2 = pa[2], a3 = pa[3];
    float4 b0 = pb[0], b1 = pb[1], b2 = pb[2], b3 = pb[3];
    float xa = x[(size_t)sa * D + lane];
    float xb = x[(size_t)sb * D + lane];
    tk[0]  += xa * a0.x; tk[1]  += xa * a0.y; tk[2]  += xa * a0.z; tk[3]  += xa * a0.w;
    tk[4]  += xa * a1.x; tk[5]  += xa * a1.y; tk[6]  += xa * a1.z; tk[7]  += xa * a1.w;
    tk[8]  += xa * a2.x; tk[9]  += xa * a2.y; tk[10] += xa * a2.z; tk[11] += xa * a2.w;
    tk[12] += xa * a3.x; tk[13] += xa * a3.y; tk[14] += xa * a3.z; tk[15] += xa * a3.w;
    if (base + 1 < en) {
      tk[0]  += xb * b0.x; tk[1]  += xb * b0.y; tk[2]  += xb * b0.z; tk[3]  += xb * b0.w;
      tk[4]  += xb * b1.x; tk[5]  += xb * b1.y; tk[6]  += xb * b1.z; tk[7]  += xb * b1.w;
      tk[8]  += xb * b2.x; tk[9]  += xb * b2.y; tk[10] += xb * b2.z; tk[11] += xb * b2.w;
      tk[12] += xb * b3.x; tk[13] += xb * b3.y; tk[14] += xb * b3.z; tk[15] += xb * b3.w;
    }
  }
  {
    float a = 0.f;
#pragma unroll
    for (int k = 0; k < DE; ++k) a += tk[k] * ew[k];
    agg0[(size_t)n * D + lane] = a;
  }
  unsigned int* tp = Tp + (size_t)n * (D * DE / 2) + lane;
#pragma unroll
  for (int j = 0; j < 8; ++j) {
    unsigned int pk = (unsigned int)f2bf(tk[2 * j]) |
                      ((unsigned int)f2bf(tk[2 * j + 1]) << 16);
    tp[(size_t)j * D] = pk;
  }
}

// ---------------- contract: aggb[je,n,d] = sum_k T[n,k,d]*We_je[k,d], T read ONCE ----------------
// All 8 expert We columns in 128 VGPRs; 2-node ILP; every load a fully-used coalesced dword.

__global__ __launch_bounds__(256, 1) void contract_kernel(
    const unsigned int* __restrict__ Tp, const float* __restrict__ ex_We,
    unsigned short* __restrict__ aggb) {
  int lane = threadIdx.x & 63;
  int w = threadIdx.x >> 6;
  float wr[NEXP][DE];
#pragma unroll
  for (int je = 0; je < NEXP; ++je)
#pragma unroll
    for (int k = 0; k < DE; ++k) wr[je][k] = ex_We[(size_t)je * DE * D + k * D + lane];

  int n0 = blockIdx.x * 64 + w * 16;
  for (int i = 0; i < 16; i += 2) {
    int nA = n0 + i, nB = n0 + i + 1;
    const unsigned int* ta = Tp + (size_t)nA * 512 + lane;
    const unsigned int* tb = Tp + (size_t)nB * 512 + lane;
    unsigned int pa[8], pb[8];
#pragma unroll
    for (int j = 0; j < 8; ++j) pa[j] = ta[(size_t)j * D];
#pragma unroll
    for (int j = 0; j < 8; ++j) pb[j] = tb[(size_t)j * D];
    float fa[DE], fb[DE];
#pragma unroll
    for (int j = 0; j < 8; ++j) {
      fa[2 * j]     = __uint_as_float(pa[j] << 16);
      fa[2 * j + 1] = __uint_as_float(pa[j] & 0xFFFF0000u);
      fb[2 * j]     = __uint_as_float(pb[j] << 16);
      fb[2 * j + 1] = __uint_as_float(pb[j] & 0xFFFF0000u);
    }
#pragma unroll
    for (int je = 0; je < NEXP; ++je) {
      float sA = 0.f, sB = 0.f;
#pragma unroll
      for (int k = 0; k < DE; ++k) { sA += fa[k] * wr[je][k]; sB += fb[k] * wr[je][k]; }
      aggb[((size_t)je * N_NODES + nA) * D + lane] = f2bf(sA);
      aggb[((size_t)je * N_NODES + nB) * D + lane] = f2bf(sB);
    }
  }
}

// ---------------- embedding GNN (j=0, exact f32, feeds routing) ----------------

__global__ __launch_bounds__(256) void gnn0_kernel(
    const float* __restrict__ x, const float* __restrict__ agg0,
    const float* __restrict__ W1, const float* __restrict__ W2,
    const float* __restrict__ bvv, float* __restrict__ graph_emb) {
  __shared__ __align__(16) float w1s[D * D];
  __shared__ __align__(16) float w2s[D * D];
  __shared__ __align__(16) float xs[D * D];
  __shared__ __align__(16) float as2[D * D];
  int b = blockIdx.x;
  int t = threadIdx.x;
  const float4* w1src = (const float4*)W1;
  const float4* w2src = (const float4*)W2;
  const float4* xsrc  = (const float4*)(x    + (size_t)b * D * D);
  const float4* asrc  = (const float4*)(agg0 + (size_t)b * D * D);
#pragma unroll
  for (int r = 0; r < 4; ++r) {
    ((float4*)w1s)[t + r * 256] = w1src[t + r * 256];
    ((float4*)w2s)[t + r * 256] = w2src[t + r * 256];
    ((float4*)xs)[t + r * 256]  = xsrc[t + r * 256];
    ((float4*)as2)[t + r * 256] = asrc[t + r * 256];
  }
  int w = t >> 6, lane = t & 63;
  float bias = bvv[lane];
  __syncthreads();
  float pool = 0.f;
#pragma unroll
  for (int q = 0; q < 4; ++q) {
    int n0 = w * 16 + q * 4;
    float a0 = bias, a1 = bias, a2 = bias, a3 = bias;
#pragma unroll 4
    for (int c4 = 0; c4 < 16; ++c4) {
      float4 x0 = *(const float4*)&xs[(n0 + 0) * D + c4 * 4];
      float4 x1 = *(const float4*)&xs[(n0 + 1) * D + c4 * 4];
      float4 x2 = *(const float4*)&xs[(n0 + 2) * D + c4 * 4];
      float4 x3 = *(const float4*)&xs[(n0 + 3) * D + c4 * 4];
      float4 g0 = *(const float4*)&as2[(n0 + 0) * D + c4 * 4];
      float4 g1 = *(const float4*)&as2[(n0 + 1) * D + c4 * 4];
      float4 g2 = *(const float4*)&as2[(n0 + 2) * D + c4 * 4];
      float4 g3 = *(const float4*)&as2[(n0 + 3) * D + c4 * 4];
      float w10 = w1s[(c4 * 4 + 0) * D + lane];
      float w11 = w1s[(c4 * 4 + 1) * D + lane];
      float w12 = w1s[(c4 * 4 + 2) * D + lane];
      float w13 = w1s[(c4 * 4 + 3) * D + lane];
      float w20 = w2s[(c4 * 4 + 0) * D + lane];
      float w21 = w2s[(c4 * 4 + 1) * D + lane];
      float w22 = w2s[(c4 * 4 + 2) * D + lane];
      float w23 = w2s[(c4 * 4 + 3) * D + lane];
      a0 += x0.x * w10 + x0.y * w11 + x0.z * w12 + x0.w * w13
          + g0.x * w20 + g0.y * w21 + g0.z * w22 + g0.w * w23;
      a1 += x1.x * w10 + x1.y * w11 + x1.z * w12 + x1.w * w13
          + g1.x * w20 + g1.y * w21 + g1.z * w22 + g1.w * w23;
      a2 += x2.x * w10 + x2.y * w11 + x2.z * w12 + x2.w * w13
          + g2.x * w20 + g2.y * w21 + g2.z * w22 + g2.w * w23;
      a3 += x3.x * w10 + x3.y * w11 + x3.z * w12 + x3.w * w13
          + g3.x * w20 + g3.y * w21 + g3.z * w22 + g3.w * w23;
    }
    pool += fmaxf(a0, 0.f) + fmaxf(a1, 0.f) + fmaxf(a2, 0.f) + fmaxf(a3, 0.f);
  }
  __syncthreads();
  xs[w * D + lane] = pool;
  __syncthreads();
  if (w == 0) {
    float s = xs[lane] + xs[D + lane] + xs[2 * D + lane] + xs[3 * D + lane];
    graph_emb[b * D + lane] = s * (1.f / 64.f);
  }
}

// ---------------- experts (MFMA) + fused gating ----------------
// block = graph, 8 waves = 8 experts; X staged once in LDS (bf16, XOR-swizzled).
// mfma_f32_16x16x32_bf16: A row=lane&15, k=(lane>>4)*8+i ; C/D col=lane&15, row=(lane>>4)*4+reg

__global__ __launch_bounds__(512) void gnn_mfma_kernel(
    const float* __restrict__ x, const unsigned short* __restrict__ aggb,
    const unsigned short* __restrict__ wpk,
    const float* __restrict__ ex_b, const float* __restrict__ ex_Wout,
    const float* __restrict__ ex_bout,
    const float* __restrict__ graph_emb, const float* __restrict__ Wg,
    const float* __restrict__ bg, float* __restrict__ out) {
  __shared__ __align__(16) short xls[4096];   // 64x64 bf16, swizzled
  __shared__ float pg[NEXP];
  __shared__ float lg[NEXP];
  int g = blockIdx.x;
  int t = threadIdx.x;
  {
    const float4* xp = (const float4*)(x + (size_t)g * 4096 + (size_t)t * 8);
    float4 va = xp[0], vb = xp[1];
    short8v pk;
    pk[0] = (short)f2bf(va.x); pk[1] = (short)f2bf(va.y);
    pk[2] = (short)f2bf(va.z); pk[3] = (short)f2bf(va.w);
    pk[4] = (short)f2bf(vb.x); pk[5] = (short)f2bf(vb.y);
    pk[6] = (short)f2bf(vb.z); pk[7] = (short)f2bf(vb.w);
    int row = t >> 3, slot = t & 7;
    *(short8v*)((char*)xls + (((row << 3) + (slot ^ (row & 7))) << 4)) = pk;
  }
  __syncthreads();

  int je = t >> 6;
  int lane = t & 63;
  int r = lane & 15, q = lane >> 4;

  const short* Ab = (const short*)(aggb + ((size_t)je * N_NODES + (size_t)g * D) * D);
  const short* B1 = (const short*)(wpk + (size_t)je * 2 * 4096);
  const short* B2 = B1 + 4096;

  floatx4 acc[4][4];
#pragma unroll
  for (int i = 0; i < 4; ++i)
#pragma unroll
    for (int j = 0; j < 4; ++j) acc[i][j] = (floatx4){0.f, 0.f, 0.f, 0.f};

  // phase 1: X(LDS) @ W1(global)
#pragma unroll
  for (int kk = 0; kk < 2; ++kk) {
    int ko = kk * 32 + q * 8;
    short8v af[4], bf[4];
#pragma unroll
    for (int rt = 0; rt < 4; ++rt) {
      int row = rt * 16 + r;
      int slot = kk * 4 + q;
      af[rt] = *(const short8v*)((char*)xls + (((row << 3) + (slot ^ (row & 7))) << 4));
    }
#pragma unroll
    for (int ct = 0; ct < 4; ++ct) bf[ct] = *(const short8v*)(B1 + (ct * 16 + r) * D + ko);
#pragma unroll
    for (int rt = 0; rt < 4; ++rt)
#pragma unroll
      for (int ct = 0; ct < 4; ++ct)
        acc[rt][ct] = __builtin_amdgcn_mfma_f32_16x16x32_bf16(af[rt], bf[ct], acc[rt][ct], 0, 0, 0);
  }
  // phase 2: AGG(global) @ W2(global)
#pragma unroll
  for (int kk = 0; kk < 2; ++kk) {
    int ko = kk * 32 + q * 8;
    short8v af[4], bf[4];
#pragma unroll
    for (int rt = 0; rt < 4; ++rt) af[rt] = *(const short8v*)(Ab + (rt * 16 + r) * D + ko);
#pragma unroll
    for (int ct = 0; ct < 4; ++ct) bf[ct] = *(const short8v*)(B2 + (ct * 16 + r) * D + ko);
#pragma unroll
    for (int rt = 0; rt < 4; ++rt)
#pragma unroll
      for (int ct = 0; ct < 4; ++ct)
        acc[rt][ct] = __builtin_amdgcn_mfma_f32_16x16x32_bf16(af[rt], bf[ct], acc[rt][ct], 0, 0, 0);
  }

  // epilogue: relu(+bias), pool over 64 rows, dot with Wout, mean, +bout -> LDS
  float o = 0.f;
#pragma unroll
  for (int ct = 0; ct < 4; ++ct) {
    float bcol = ex_b[je * D + ct * 16 + r];
    float s = 0.f;
#pragma unroll
    for (int rt = 0; rt < 4; ++rt)
#pragma unroll
      for (int rg = 0; rg < 4; ++rg) s += fmaxf(acc[rt][ct][rg] + bcol, 0.f);
    s += __shfl_xor(s, 16);
    s += __shfl_xor(s, 32);
    o += s * ex_Wout[je * D + ct * 16 + r];
  }
#pragma unroll
  for (int off = 8; off >= 1; off >>= 1) o += __shfl_xor(o, off);
  if (lane == 0) pg[je] = o * (1.f / 64.f) + ex_bout[je];
  __syncthreads();

  // fused gating (exact f32): reuse xls as float scratch for graph_emb row
  float* es = (float*)xls;
  if (t < 64) es[t] = graph_emb[g * D + t];
  __syncthreads();
  if (t < NEXP) {
    float v = bg[t];
    for (int d = 0; d < D; ++d) v += es[d] * Wg[d * NEXP + t];
    lg[t] = v;
  }
  __syncthreads();
  if (t < NEXP) {
    float l[NEXP];
    float mx = -1e30f;
#pragma unroll
    for (int e = 0; e < NEXP; ++e) { l[e] = lg[e]; mx = fmaxf(mx, l[e]); }
    float p[NEXP];
    float sum = 0.f;
#pragma unroll
    for (int e = 0; e < NEXP; ++e) { p[e] = expf(l[e] - mx); sum += p[e]; }
    float inv = 1.f / sum;
#pragma unroll
    for (int e = 0; e < NEXP; ++e) p[e] *= inv;
    out[NB + g * NEXP + t] = p[t];
    if (t == 0) {
      int i1 = -1; float v1 = -1e30f;
#pragma unroll
      for (int e = 0; e < NEXP; ++e) if (p[e] > v1) { v1 = p[e]; i1 = e; }
      int i2 = -1; float v2 = -1e30f;
#pragma unroll
      for (int e = 0; e < NEXP; ++e) if (e != i1 && p[e] > v2) { v2 = p[e]; i2 = e; }
      float rr = expf(v2 - v1);
      float n1 = 1.f / (1.f + rr);
      float n2 = rr / (1.f + rr);
      out[g] = n1 * pg[i1] + n2 * pg[i2];
    }
  }
}

// ---------------- launch ----------------

extern "C" void kernel_launch(void* const* d_in, const int* in_sizes, int n_in,
                              void* d_out, int out_size, void* d_ws, size_t ws_size,
                              hipStream_t stream) {
  const float* x         = (const float*)d_in[0];
  const float* edge_attr = (const float*)d_in[1];
  const float* emb_We    = (const float*)d_in[2];
  const float* emb_W1    = (const float*)d_in[3];
  const float* emb_W2    = (const float*)d_in[4];
  const float* emb_b     = (const float*)d_in[5];
  const float* Wg        = (const float*)d_in[6];
  const float* bg        = (const float*)d_in[7];
  const float* ex_We     = (const float*)d_in[8];
  const float* ex_W1     = (const float*)d_in[9];
  const float* ex_W2     = (const float*)d_in[10];
  const float* ex_b      = (const float*)d_in[11];
  const float* ex_Wout   = (const float*)d_in[12];
  const float* ex_bout   = (const float*)d_in[13];
  const int* edge_src    = (const int*)d_in[14];
  const int* edge_dst    = (const int*)d_in[15];

  char* p = (char*)d_ws;
  auto alloc = [&](size_t bytes) {
    char* q = p;
    p += (bytes + 255) & ~(size_t)255;
    return q;
  };
  int*   counts     = (int*)alloc((size_t)N_NODES * 4);
  int*   offsets    = (int*)alloc((size_t)(N_NODES + 1) * 4);
  int*   cursor     = (int*)alloc((size_t)N_NODES * 4);
  int*   bsums      = (int*)alloc(128 * 4);
  int*   sorted_src = (int*)alloc((size_t)N_EDGES * 4);
  float* sorted_ea  = (float*)alloc((size_t)N_EDGES * DE * 4);
  unsigned int* Tp  = (unsigned int*)alloc((size_t)N_NODES * (D * DE / 2) * 4);  // 64 MB
  float* agg0       = (float*)alloc((size_t)N_NODES * D * 4);
  unsigned short* aggb = (unsigned short*)alloc((size_t)NEXP * N_NODES * D * 2);
  unsigned short* wpk  = (unsigned short*)alloc((size_t)NEXP * 2 * D * D * 2);
  float* graph_emb  = (float*)alloc((size_t)NB * D * 4);

  hipMemsetAsync(counts, 0, (size_t)N_NODES * 4, stream);
  hist_kernel<<<N_EDGES / 256, 256, 0, stream>>>(edge_dst, counts);
  scan1_kernel<<<N_NODES / 256, 256, 0, stream>>>(counts, offsets, bsums);
  scan2_kernel<<<1, 128, 0, stream>>>(bsums);
  scan3_kernel<<<N_NODES / 256, 256, 0, stream>>>(offsets, bsums, cursor);
  scatter_kernel<<<N_EDGES / 256, 256, 0, stream>>>(edge_dst, edge_src,
                                                    (const float4*)edge_attr, cursor,
                                                    sorted_src, (float4*)sorted_ea,
                                                    ex_W1, ex_W2, wpk);
  tkern<<<N_NODES / 4, 256, 0, stream>>>(x, sorted_src, (const float4*)sorted_ea,
                                         offsets, emb_We, agg0, Tp);
  contract_kernel<<<N_NODES / 64, 256, 0, stream>>>(Tp, ex_We, aggb);
  gnn0_kernel<<<NB, 256, 0, stream>>>(x, agg0, emb_W1, emb_W2, emb_b, graph_emb);
  gnn_mfma_kernel<<<NB, 512, 0, stream>>>(x, aggb, wpk, ex_b, ex_Wout, ex_bout,
                                          graph_emb, Wg, bg, (float*)d_out);
}

// Round 8
// 222.224 us; speedup vs baseline: 1.9186x; 1.1138x over previous
//
#include <hip/hip_runtime.h>

#define N_NODES 32768
#define N_EDGES 262144
#define NB      512
#define D       64
#define DE      16
#define NEXP    8

typedef __attribute__((ext_vector_type(8))) short  short8v;
typedef __attribute__((ext_vector_type(4))) float  floatx4;

static __device__ __forceinline__ unsigned short f2bf(float f) {
  unsigned int u = __float_as_uint(f);
  u += 0x7FFFu + ((u >> 16) & 1u);
  return (unsigned short)(u >> 16);
}

// ---------------- sort edges by dst ----------------

__global__ void hist_kernel(const int* __restrict__ dst, int* __restrict__ counts) {
  int i = blockIdx.x * blockDim.x + threadIdx.x;
  if (i < N_EDGES) atomicAdd(&counts[dst[i]], 1);
}

__global__ void scan1_kernel(const int* __restrict__ counts, int* __restrict__ offsets,
                             int* __restrict__ bsums) {
  __shared__ int sm[256];
  int t = threadIdx.x, i = blockIdx.x * 256 + t;
  int v = counts[i];
  sm[t] = v;
  __syncthreads();
  for (int off = 1; off < 256; off <<= 1) {
    int u = (t >= off) ? sm[t - off] : 0;
    __syncthreads();
    sm[t] += u;
    __syncthreads();
  }
  offsets[i] = sm[t] - v;              // in-block exclusive
  if (t == 255) bsums[blockIdx.x] = sm[255];
}

__global__ void scan2_kernel(int* __restrict__ bsums) {
  __shared__ int sm[128];
  int t = threadIdx.x;
  int v = bsums[t];
  sm[t] = v;
  __syncthreads();
  for (int off = 1; off < 128; off <<= 1) {
    int u = (t >= off) ? sm[t - off] : 0;
    __syncthreads();
    sm[t] += u;
    __syncthreads();
  }
  bsums[t] = sm[t] - v;                // exclusive block offsets
}

__global__ void scan3_kernel(int* __restrict__ offsets, const int* __restrict__ bsums,
                             int* __restrict__ cursor) {
  int i = blockIdx.x * 256 + threadIdx.x;
  int v = offsets[i] + bsums[blockIdx.x];
  offsets[i] = v;
  cursor[i]  = v;
  if (i == 0) offsets[N_NODES] = N_EDGES;
}

// scatter sorted payload (+ fused weight pack in spare thread range)
__global__ void scatter_kernel(const int* __restrict__ dst, const int* __restrict__ src,
                               const float4* __restrict__ ea4, int* __restrict__ cursor,
                               int* __restrict__ sorted_src, float4* __restrict__ sea4,
                               const float* __restrict__ ex_W1, const float* __restrict__ ex_W2,
                               unsigned short* __restrict__ wpk) {
  int i = blockIdx.x * blockDim.x + threadIdx.x;
  if (i < N_EDGES) {
    int p = atomicAdd(&cursor[dst[i]], 1);
    sorted_src[p] = src[i];
    float4 a = ea4[(size_t)i * 4 + 0];
    float4 b = ea4[(size_t)i * 4 + 1];
    float4 c = ea4[(size_t)i * 4 + 2];
    float4 d = ea4[(size_t)i * 4 + 3];
    sea4[(size_t)p * 4 + 0] = a;
    sea4[(size_t)p * 4 + 1] = b;
    sea4[(size_t)p * 4 + 2] = c;
    sea4[(size_t)p * 4 + 3] = d;
  }
  if (i < NEXP * 2 * D * D) {          // wpk[je][mat][col][k] = W_mat_je[k][col]
    int je  = i >> 13;
    int rem = i & 8191;
    int mat = rem >> 12;
    int cd  = rem & 4095;
    int col = cd >> 6, k = cd & 63;
    const float* W = mat ? ex_W2 : ex_W1;
    wpk[i] = f2bf(W[je * 4096 + k * 64 + col]);
  }
}

// ---------------- tkern: 2 nodes per wave, scalar-uniform edge stream ----------------
// wave handles nodes n0, n1. All edge indices rooted in SGPRs (readfirstlane) so
// sorted_src / sea4 loads take the scalar path; two independent chains for MLP.
// Loads unconditional (clamped), contributions masked -> no conditional-load serialization.

__global__ __launch_bounds__(256) void tkern(
    const float* __restrict__ x, const int* __restrict__ sorted_src,
    const float4* __restrict__ sea4, const int* __restrict__ offsets,
    const float* __restrict__ emb_We, float* __restrict__ agg0,
    unsigned int* __restrict__ Tp) {
  int lane = threadIdx.x & 63;
  int wv = threadIdx.x >> 6;
  int n0 = blockIdx.x * 8 + wv * 2;
  int n1 = n0 + 1;
  int st0 = __builtin_amdgcn_readfirstlane(offsets[n0]);
  int en0 = __builtin_amdgcn_readfirstlane(offsets[n0 + 1]);
  int en1 = __builtin_amdgcn_readfirstlane(offsets[n1 + 1]);
  int b0 = st0, b1 = en0;

  float tk0[DE], tk1[DE];
#pragma unroll
  for (int k = 0; k < DE; ++k) { tk0[k] = 0.f; tk1[k] = 0.f; }

  while (b0 < en0 || b1 < en1) {
    int e00 = (b0     < N_EDGES - 1) ? b0     : N_EDGES - 1;
    int e01 = (b0 + 1 < N_EDGES - 1) ? b0 + 1 : N_EDGES - 1;
    int e10 = (b1     < N_EDGES - 1) ? b1     : N_EDGES - 1;
    int e11 = (b1 + 1 < N_EDGES - 1) ? b1 + 1 : N_EDGES - 1;
    float m00 = (b0     < en0) ? 1.f : 0.f;
    float m01 = (b0 + 1 < en0) ? 1.f : 0.f;
    float m10 = (b1     < en1) ? 1.f : 0.f;
    float m11 = (b1 + 1 < en1) ? 1.f : 0.f;
    int s00 = sorted_src[e00];
    int s01 = sorted_src[e01];
    int s10 = sorted_src[e10];
    int s11 = sorted_src[e11];
    const float4* p00 = sea4 + ((size_t)e00 << 2);
    const float4* p01 = sea4 + ((size_t)e01 << 2);
    const float4* p10 = sea4 + ((size_t)e10 << 2);
    const float4* p11 = sea4 + ((size_t)e11 << 2);
    float4 a0 = p00[0], a1 = p00[1], a2 = p00[2], a3 = p00[3];
    float4 c0 = p01[0], c1 = p01[1], c2 = p01[2], c3 = p01[3];
    float4 d0 = p10[0], d1 = p10[1], d2 = p10[2], d3 = p10[3];
    float4 f0 = p11[0], f1 = p11[1], f2 = p11[2], f3 = p11[3];
    float x00 = x[(size_t)s00 * D + lane] * m00;
    float x01 = x[(size_t)s01 * D + lane] * m01;
    float x10 = x[(size_t)s10 * D + lane] * m10;
    float x11 = x[(size_t)s11 * D + lane] * m11;

    tk0[0]  += x00 * a0.x; tk0[1]  += x00 * a0.y; tk0[2]  += x00 * a0.z; tk0[3]  += x00 * a0.w;
    tk0[4]  += x00 * a1.x; tk0[5]  += x00 * a1.y; tk0[6]  += x00 * a1.z; tk0[7]  += x00 * a1.w;
    tk0[8]  += x00 * a2.x; tk0[9]  += x00 * a2.y; tk0[10] += x00 * a2.z; tk0[11] += x00 * a2.w;
    tk0[12] += x00 * a3.x; tk0[13] += x00 * a3.y; tk0[14] += x00 * a3.z; tk0[15] += x00 * a3.w;
    tk0[0]  += x01 * c0.x; tk0[1]  += x01 * c0.y; tk0[2]  += x01 * c0.z; tk0[3]  += x01 * c0.w;
    tk0[4]  += x01 * c1.x; tk0[5]  += x01 * c1.y; tk0[6]  += x01 * c1.z; tk0[7]  += x01 * c1.w;
    tk0[8]  += x01 * c2.x; tk0[9]  += x01 * c2.y; tk0[10] += x01 * c2.z; tk0[11] += x01 * c2.w;
    tk0[12] += x01 * c3.x; tk0[13] += x01 * c3.y; tk0[14] += x01 * c3.z; tk0[15] += x01 * c3.w;
    tk1[0]  += x10 * d0.x; tk1[1]  += x10 * d0.y; tk1[2]  += x10 * d0.z; tk1[3]  += x10 * d0.w;
    tk1[4]  += x10 * d1.x; tk1[5]  += x10 * d1.y; tk1[6]  += x10 * d1.z; tk1[7]  += x10 * d1.w;
    tk1[8]  += x10 * d2.x; tk1[9]  += x10 * d2.y; tk1[10] += x10 * d2.z; tk1[11] += x10 * d2.w;
    tk1[12] += x10 * d3.x; tk1[13] += x10 * d3.y; tk1[14] += x10 * d3.z; tk1[15] += x10 * d3.w;
    tk1[0]  += x11 * f0.x; tk1[1]  += x11 * f0.y; tk1[2]  += x11 * f0.z; tk1[3]  += x11 * f0.w;
    tk1[4]  += x11 * f1.x; tk1[5]  += x11 * f1.y; tk1[6]  += x11 * f1.z; tk1[7]  += x11 * f1.w;
    tk1[8]  += x11 * f2.x; tk1[9]  += x11 * f2.y; tk1[10] += x11 * f2.z; tk1[11] += x11 * f2.w;
    tk1[12] += x11 * f3.x; tk1[13] += x11 * f3.y; tk1[14] += x11 * f3.z; tk1[15] += x11 * f3.w;
    b0 += 2; b1 += 2;
  }

  {
    float av0 = 0.f, av1 = 0.f;
#pragma unroll
    for (int k = 0; k < DE; ++k) {
      float ewk = emb_We[k * D + lane];
      av0 += tk0[k] * ewk;
      av1 += tk1[k] * ewk;
    }
    agg0[(size_t)n0 * D + lane] = av0;
    agg0[(size_t)n1 * D + lane] = av1;
  }
  unsigned int* tp0 = Tp + (size_t)n0 * (D * DE / 2) + lane;
  unsigned int* tp1 = Tp + (size_t)n1 * (D * DE / 2) + lane;
#pragma unroll
  for (int j = 0; j < 8; ++j) {
    unsigned int pk0 = (unsigned int)f2bf(tk0[2 * j]) |
                       ((unsigned int)f2bf(tk0[2 * j + 1]) << 16);
    unsigned int pk1 = (unsigned int)f2bf(tk1[2 * j]) |
                       ((unsigned int)f2bf(tk1[2 * j + 1]) << 16);
    tp0[(size_t)j * D] = pk0;
    tp1[(size_t)j * D] = pk1;
  }
}

// ---------------- contract v2: wave-per-expert, 16-reg We column, no big arrays ----------------
// block = 512 thr = 8 waves; wave je handles expert je for this block's 64 nodes.

__global__ __launch_bounds__(512) void contract_kernel(
    const unsigned int* __restrict__ Tp, const float* __restrict__ ex_We,
    unsigned short* __restrict__ aggb) {
  int lane = threadIdx.x & 63;
  int je = threadIdx.x >> 6;            // 0..7
  float wr[DE];
#pragma unroll
  for (int k = 0; k < DE; ++k) wr[k] = ex_We[(size_t)je * DE * D + k * D + lane];

  int n0 = blockIdx.x * 64;
  unsigned short* ob = aggb + (size_t)je * N_NODES * D;
  for (int i = 0; i < 64; i += 2) {
    int nA = n0 + i, nB = n0 + i + 1;
    const unsigned int* ta = Tp + (size_t)nA * 512 + lane;
    const unsigned int* tb = Tp + (size_t)nB * 512 + lane;
    unsigned int pa0 = ta[0],   pa1 = ta[64],  pa2 = ta[128], pa3 = ta[192];
    unsigned int pa4 = ta[256], pa5 = ta[320], pa6 = ta[384], pa7 = ta[448];
    unsigned int pb0 = tb[0],   pb1 = tb[64],  pb2 = tb[128], pb3 = tb[192];
    unsigned int pb4 = tb[256], pb5 = tb[320], pb6 = tb[384], pb7 = tb[448];
    float sA, sB;
    sA  = __uint_as_float(pa0 << 16)         * wr[0];
    sA += __uint_as_float(pa0 & 0xFFFF0000u) * wr[1];
    sA += __uint_as_float(pa1 << 16)         * wr[2];
    sA += __uint_as_float(pa1 & 0xFFFF0000u) * wr[3];
    sA += __uint_as_float(pa2 << 16)         * wr[4];
    sA += __uint_as_float(pa2 & 0xFFFF0000u) * wr[5];
    sA += __uint_as_float(pa3 << 16)         * wr[6];
    sA += __uint_as_float(pa3 & 0xFFFF0000u) * wr[7];
    sA += __uint_as_float(pa4 << 16)         * wr[8];
    sA += __uint_as_float(pa4 & 0xFFFF0000u) * wr[9];
    sA += __uint_as_float(pa5 << 16)         * wr[10];
    sA += __uint_as_float(pa5 & 0xFFFF0000u) * wr[11];
    sA += __uint_as_float(pa6 << 16)         * wr[12];
    sA += __uint_as_float(pa6 & 0xFFFF0000u) * wr[13];
    sA += __uint_as_float(pa7 << 16)         * wr[14];
    sA += __uint_as_float(pa7 & 0xFFFF0000u) * wr[15];
    sB  = __uint_as_float(pb0 << 16)         * wr[0];
    sB += __uint_as_float(pb0 & 0xFFFF0000u) * wr[1];
    sB += __uint_as_float(pb1 << 16)         * wr[2];
    sB += __uint_as_float(pb1 & 0xFFFF0000u) * wr[3];
    sB += __uint_as_float(pb2 << 16)         * wr[4];
    sB += __uint_as_float(pb2 & 0xFFFF0000u) * wr[5];
    sB += __uint_as_float(pb3 << 16)         * wr[6];
    sB += __uint_as_float(pb3 & 0xFFFF0000u) * wr[7];
    sB += __uint_as_float(pb4 << 16)         * wr[8];
    sB += __uint_as_float(pb4 & 0xFFFF0000u) * wr[9];
    sB += __uint_as_float(pb5 << 16)         * wr[10];
    sB += __uint_as_float(pb5 & 0xFFFF0000u) * wr[11];
    sB += __uint_as_float(pb6 << 16)         * wr[12];
    sB += __uint_as_float(pb6 & 0xFFFF0000u) * wr[13];
    sB += __uint_as_float(pb7 << 16)         * wr[14];
    sB += __uint_as_float(pb7 & 0xFFFF0000u) * wr[15];
    ob[(size_t)nA * D + lane] = f2bf(sA);
    ob[(size_t)nB * D + lane] = f2bf(sB);
  }
}

// ---------------- embedding GNN (j=0, exact f32, feeds routing) ----------------

__global__ __launch_bounds__(256) void gnn0_kernel(
    const float* __restrict__ x, const float* __restrict__ agg0,
    const float* __restrict__ W1, const float* __restrict__ W2,
    const float* __restrict__ bvv, float* __restrict__ graph_emb) {
  __shared__ __align__(16) float w1s[D * D];
  __shared__ __align__(16) float w2s[D * D];
  __shared__ __align__(16) float xs[D * D];
  __shared__ __align__(16) float as2[D * D];
  int b = blockIdx.x;
  int t = threadIdx.x;
  const float4* w1src = (const float4*)W1;
  const float4* w2src = (const float4*)W2;
  const float4* xsrc  = (const float4*)(x    + (size_t)b * D * D);
  const float4* asrc  = (const float4*)(agg0 + (size_t)b * D * D);
#pragma unroll
  for (int r = 0; r < 4; ++r) {
    ((float4*)w1s)[t + r * 256] = w1src[t + r * 256];
    ((float4*)w2s)[t + r * 256] = w2src[t + r * 256];
    ((float4*)xs)[t + r * 256]  = xsrc[t + r * 256];
    ((float4*)as2)[t + r * 256] = asrc[t + r * 256];
  }
  int w = t >> 6, lane = t & 63;
  float bias = bvv[lane];
  __syncthreads();
  float pool = 0.f;
#pragma unroll
  for (int q = 0; q < 4; ++q) {
    int n0 = w * 16 + q * 4;
    float a0 = bias, a1 = bias, a2 = bias, a3 = bias;
#pragma unroll 4
    for (int c4 = 0; c4 < 16; ++c4) {
      float4 x0 = *(const float4*)&xs[(n0 + 0) * D + c4 * 4];
      float4 x1 = *(const float4*)&xs[(n0 + 1) * D + c4 * 4];
      float4 x2 = *(const float4*)&xs[(n0 + 2) * D + c4 * 4];
      float4 x3 = *(const float4*)&xs[(n0 + 3) * D + c4 * 4];
      float4 g0 = *(const float4*)&as2[(n0 + 0) * D + c4 * 4];
      float4 g1 = *(const float4*)&as2[(n0 + 1) * D + c4 * 4];
      float4 g2 = *(const float4*)&as2[(n0 + 2) * D + c4 * 4];
      float4 g3 = *(const float4*)&as2[(n0 + 3) * D + c4 * 4];
      float w10 = w1s[(c4 * 4 + 0) * D + lane];
      float w11 = w1s[(c4 * 4 + 1) * D + lane];
      float w12 = w1s[(c4 * 4 + 2) * D + lane];
      float w13 = w1s[(c4 * 4 + 3) * D + lane];
      float w20 = w2s[(c4 * 4 + 0) * D + lane];
      float w21 = w2s[(c4 * 4 + 1) * D + lane];
      float w22 = w2s[(c4 * 4 + 2) * D + lane];
      float w23 = w2s[(c4 * 4 + 3) * D + lane];
      a0 += x0.x * w10 + x0.y * w11 + x0.z * w12 + x0.w * w13
          + g0.x * w20 + g0.y * w21 + g0.z * w22 + g0.w * w23;
      a1 += x1.x * w10 + x1.y * w11 + x1.z * w12 + x1.w * w13
          + g1.x * w20 + g1.y * w21 + g1.z * w22 + g1.w * w23;
      a2 += x2.x * w10 + x2.y * w11 + x2.z * w12 + x2.w * w13
          + g2.x * w20 + g2.y * w21 + g2.z * w22 + g2.w * w23;
      a3 += x3.x * w10 + x3.y * w11 + x3.z * w12 + x3.w * w13
          + g3.x * w20 + g3.y * w21 + g3.z * w22 + g3.w * w23;
    }
    pool += fmaxf(a0, 0.f) + fmaxf(a1, 0.f) + fmaxf(a2, 0.f) + fmaxf(a3, 0.f);
  }
  __syncthreads();
  xs[w * D + lane] = pool;
  __syncthreads();
  if (w == 0) {
    float s = xs[lane] + xs[D + lane] + xs[2 * D + lane] + xs[3 * D + lane];
    graph_emb[b * D + lane] = s * (1.f / 64.f);
  }
}

// ---------------- experts (MFMA) + fused gating ----------------
// block = graph, 8 waves = 8 experts; X staged once in LDS (bf16, XOR-swizzled).
// mfma_f32_16x16x32_bf16: A row=lane&15, k=(lane>>4)*8+i ; C/D col=lane&15, row=(lane>>4)*4+reg

__global__ __launch_bounds__(512) void gnn_mfma_kernel(
    const float* __restrict__ x, const unsigned short* __restrict__ aggb,
    const unsigned short* __restrict__ wpk,
    const float* __restrict__ ex_b, const float* __restrict__ ex_Wout,
    const float* __restrict__ ex_bout,
    const float* __restrict__ graph_emb, const float* __restrict__ Wg,
    const float* __restrict__ bg, float* __restrict__ out) {
  __shared__ __align__(16) short xls[4096];   // 64x64 bf16, swizzled
  __shared__ float pg[NEXP];
  __shared__ float lg[NEXP];
  int g = blockIdx.x;
  int t = threadIdx.x;
  {
    const float4* xp = (const float4*)(x + (size_t)g * 4096 + (size_t)t * 8);
    float4 va = xp[0], vb = xp[1];
    short8v pk;
    pk[0] = (short)f2bf(va.x); pk[1] = (short)f2bf(va.y);
    pk[2] = (short)f2bf(va.z); pk[3] = (short)f2bf(va.w);
    pk[4] = (short)f2bf(vb.x); pk[5] = (short)f2bf(vb.y);
    pk[6] = (short)f2bf(vb.z); pk[7] = (short)f2bf(vb.w);
    int row = t >> 3, slot = t & 7;
    *(short8v*)((char*)xls + (((row << 3) + (slot ^ (row & 7))) << 4)) = pk;
  }
  __syncthreads();

  int je = t >> 6;
  int lane = t & 63;
  int r = lane & 15, q = lane >> 4;

  const short* Ab = (const short*)(aggb + ((size_t)je * N_NODES + (size_t)g * D) * D);
  const short* B1 = (const short*)(wpk + (size_t)je * 2 * 4096);
  const short* B2 = B1 + 4096;

  floatx4 acc[4][4];
#pragma unroll
  for (int i = 0; i < 4; ++i)
#pragma unroll
    for (int j = 0; j < 4; ++j) acc[i][j] = (floatx4){0.f, 0.f, 0.f, 0.f};

  // phase 1: X(LDS) @ W1(global)
#pragma unroll
  for (int kk = 0; kk < 2; ++kk) {
    int ko = kk * 32 + q * 8;
    short8v af[4], bf[4];
#pragma unroll
    for (int rt = 0; rt < 4; ++rt) {
      int row = rt * 16 + r;
      int slot = kk * 4 + q;
      af[rt] = *(const short8v*)((char*)xls + (((row << 3) + (slot ^ (row & 7))) << 4));
    }
#pragma unroll
    for (int ct = 0; ct < 4; ++ct) bf[ct] = *(const short8v*)(B1 + (ct * 16 + r) * D + ko);
#pragma unroll
    for (int rt = 0; rt < 4; ++rt)
#pragma unroll
      for (int ct = 0; ct < 4; ++ct)
        acc[rt][ct] = __builtin_amdgcn_mfma_f32_16x16x32_bf16(af[rt], bf[ct], acc[rt][ct], 0, 0, 0);
  }
  // phase 2: AGG(global) @ W2(global)
#pragma unroll
  for (int kk = 0; kk < 2; ++kk) {
    int ko = kk * 32 + q * 8;
    short8v af[4], bf[4];
#pragma unroll
    for (int rt = 0; rt < 4; ++rt) af[rt] = *(const short8v*)(Ab + (rt * 16 + r) * D + ko);
#pragma unroll
    for (int ct = 0; ct < 4; ++ct) bf[ct] = *(const short8v*)(B2 + (ct * 16 + r) * D + ko);
#pragma unroll
    for (int rt = 0; rt < 4; ++rt)
#pragma unroll
      for (int ct = 0; ct < 4; ++ct)
        acc[rt][ct] = __builtin_amdgcn_mfma_f32_16x16x32_bf16(af[rt], bf[ct], acc[rt][ct], 0, 0, 0);
  }

  // epilogue: relu(+bias), pool over 64 rows, dot with Wout, mean, +bout -> LDS
  float o = 0.f;
#pragma unroll
  for (int ct = 0; ct < 4; ++ct) {
    float bcol = ex_b[je * D + ct * 16 + r];
    float s = 0.f;
#pragma unroll
    for (int rt = 0; rt < 4; ++rt)
#pragma unroll
      for (int rg = 0; rg < 4; ++rg) s += fmaxf(acc[rt][ct][rg] + bcol, 0.f);
    s += __shfl_xor(s, 16);
    s += __shfl_xor(s, 32);
    o += s * ex_Wout[je * D + ct * 16 + r];
  }
#pragma unroll
  for (int off = 8; off >= 1; off >>= 1) o += __shfl_xor(o, off);
  if (lane == 0) pg[je] = o * (1.f / 64.f) + ex_bout[je];
  __syncthreads();

  // fused gating (exact f32): reuse xls as float scratch for graph_emb row
  float* es = (float*)xls;
  if (t < 64) es[t] = graph_emb[g * D + t];
  __syncthreads();
  if (t < NEXP) {
    float v = bg[t];
    for (int d = 0; d < D; ++d) v += es[d] * Wg[d * NEXP + t];
    lg[t] = v;
  }
  __syncthreads();
  if (t < NEXP) {
    float l[NEXP];
    float mx = -1e30f;
#pragma unroll
    for (int e = 0; e < NEXP; ++e) { l[e] = lg[e]; mx = fmaxf(mx, l[e]); }
    float p[NEXP];
    float sum = 0.f;
#pragma unroll
    for (int e = 0; e < NEXP; ++e) { p[e] = expf(l[e] - mx); sum += p[e]; }
    float inv = 1.f / sum;
#pragma unroll
    for (int e = 0; e < NEXP; ++e) p[e] *= inv;
    out[NB + g * NEXP + t] = p[t];
    if (t == 0) {
      int i1 = -1; float v1 = -1e30f;
#pragma unroll
      for (int e = 0; e < NEXP; ++e) if (p[e] > v1) { v1 = p[e]; i1 = e; }
      int i2 = -1; float v2 = -1e30f;
#pragma unroll
      for (int e = 0; e < NEXP; ++e) if (e != i1 && p[e] > v2) { v2 = p[e]; i2 = e; }
      float rr = expf(v2 - v1);
      float n1 = 1.f / (1.f + rr);
      float n2 = rr / (1.f + rr);
      out[g] = n1 * pg[i1] + n2 * pg[i2];
    }
  }
}

// ---------------- launch ----------------

extern "C" void kernel_launch(void* const* d_in, const int* in_sizes, int n_in,
                              void* d_out, int out_size, void* d_ws, size_t ws_size,
                              hipStream_t stream) {
  const float* x         = (const float*)d_in[0];
  const float* edge_attr = (const float*)d_in[1];
  const float* emb_We    = (const float*)d_in[2];
  const float* emb_W1    = (const float*)d_in[3];
  const float* emb_W2    = (const float*)d_in[4];
  const float* emb_b     = (const float*)d_in[5];
  const float* Wg        = (const float*)d_in[6];
  const float* bg        = (const float*)d_in[7];
  const float* ex_We     = (const float*)d_in[8];
  const float* ex_W1     = (const float*)d_in[9];
  const float* ex_W2     = (const float*)d_in[10];
  const float* ex_b      = (const float*)d_in[11];
  const float* ex_Wout   = (const float*)d_in[12];
  const float* ex_bout   = (const float*)d_in[13];
  const int* edge_src    = (const int*)d_in[14];
  const int* edge_dst    = (const int*)d_in[15];

  char* p = (char*)d_ws;
  auto alloc = [&](size_t bytes) {
    char* q = p;
    p += (bytes + 255) & ~(size_t)255;
    return q;
  };
  int*   counts     = (int*)alloc((size_t)N_NODES * 4);
  int*   offsets    = (int*)alloc((size_t)(N_NODES + 1) * 4);
  int*   cursor     = (int*)alloc((size_t)N_NODES * 4);
  int*   bsums      = (int*)alloc(128 * 4);
  int*   sorted_src = (int*)alloc((size_t)N_EDGES * 4);
  float* sorted_ea  = (float*)alloc((size_t)N_EDGES * DE * 4);
  unsigned int* Tp  = (unsigned int*)alloc((size_t)N_NODES * (D * DE / 2) * 4);  // 64 MB
  float* agg0       = (float*)alloc((size_t)N_NODES * D * 4);
  unsigned short* aggb = (unsigned short*)alloc((size_t)NEXP * N_NODES * D * 2);
  unsigned short* wpk  = (unsigned short*)alloc((size_t)NEXP * 2 * D * D * 2);
  float* graph_emb  = (float*)alloc((size_t)NB * D * 4);

  hipMemsetAsync(counts, 0, (size_t)N_NODES * 4, stream);
  hist_kernel<<<N_EDGES / 256, 256, 0, stream>>>(edge_dst, counts);
  scan1_kernel<<<N_NODES / 256, 256, 0, stream>>>(counts, offsets, bsums);
  scan2_kernel<<<1, 128, 0, stream>>>(bsums);
  scan3_kernel<<<N_NODES / 256, 256, 0, stream>>>(offsets, bsums, cursor);
  scatter_kernel<<<N_EDGES / 256, 256, 0, stream>>>(edge_dst, edge_src,
                                                    (const float4*)edge_attr, cursor,
                                                    sorted_src, (float4*)sorted_ea,
                                                    ex_W1, ex_W2, wpk);
  tkern<<<N_NODES / 8, 256, 0, stream>>>(x, sorted_src, (const float4*)sorted_ea,
                                         offsets, emb_We, agg0, Tp);
  contract_kernel<<<N_NODES / 64, 512, 0, stream>>>(Tp, ex_We, aggb);
  gnn0_kernel<<<NB, 256, 0, stream>>>(x, agg0, emb_W1, emb_W2, emb_b, graph_emb);
  gnn_mfma_kernel<<<NB, 512, 0, stream>>>(x, aggb, wpk, ex_b, ex_Wout, ex_bout,
                                          graph_emb, Wg, bg, (float*)d_out);
}

// Round 9
// 210.179 us; speedup vs baseline: 2.0286x; 1.0573x over previous
//
#include <hip/hip_runtime.h>

#define N_NODES 32768
#define N_EDGES 262144
#define NB      512
#define D       64
#define DE      16
#define NEXP    8

typedef __attribute__((ext_vector_type(8))) short  short8v;
typedef __attribute__((ext_vector_type(4))) float  floatx4;

static __device__ __forceinline__ unsigned short f2bf(float f) {
  unsigned int u = __float_as_uint(f);
  u += 0x7FFFu + ((u >> 16) & 1u);
  return (unsigned short)(u >> 16);
}

// ---------------- sort edges by dst ----------------

__global__ void hist_kernel(const int* __restrict__ dst, int* __restrict__ counts) {
  int i = blockIdx.x * blockDim.x + threadIdx.x;
  if (i < N_EDGES) atomicAdd(&counts[dst[i]], 1);
}

__global__ void scan1_kernel(const int* __restrict__ counts, int* __restrict__ offsets,
                             int* __restrict__ bsums) {
  __shared__ int sm[256];
  int t = threadIdx.x, i = blockIdx.x * 256 + t;
  int v = counts[i];
  sm[t] = v;
  __syncthreads();
  for (int off = 1; off < 256; off <<= 1) {
    int u = (t >= off) ? sm[t - off] : 0;
    __syncthreads();
    sm[t] += u;
    __syncthreads();
  }
  offsets[i] = sm[t] - v;              // in-block exclusive
  if (t == 255) bsums[blockIdx.x] = sm[255];
}

__global__ void scan2_kernel(int* __restrict__ bsums) {
  __shared__ int sm[128];
  int t = threadIdx.x;
  int v = bsums[t];
  sm[t] = v;
  __syncthreads();
  for (int off = 1; off < 128; off <<= 1) {
    int u = (t >= off) ? sm[t - off] : 0;
    __syncthreads();
    sm[t] += u;
    __syncthreads();
  }
  bsums[t] = sm[t] - v;                // exclusive block offsets
}

__global__ void scan3_kernel(int* __restrict__ offsets, const int* __restrict__ bsums,
                             int* __restrict__ cursor) {
  int i = blockIdx.x * 256 + threadIdx.x;
  int v = offsets[i] + bsums[blockIdx.x];
  offsets[i] = v;
  cursor[i]  = v;
  if (i == 0) offsets[N_NODES] = N_EDGES;
}

// scatter sorted payload (+ fused weight pack in spare thread range)
__global__ void scatter_kernel(const int* __restrict__ dst, const int* __restrict__ src,
                               const float4* __restrict__ ea4, int* __restrict__ cursor,
                               int* __restrict__ sorted_src, float4* __restrict__ sea4,
                               const float* __restrict__ ex_W1, const float* __restrict__ ex_W2,
                               unsigned short* __restrict__ wpk) {
  int i = blockIdx.x * blockDim.x + threadIdx.x;
  if (i < N_EDGES) {
    int p = atomicAdd(&cursor[dst[i]], 1);
    sorted_src[p] = src[i];
    float4 a = ea4[(size_t)i * 4 + 0];
    float4 b = ea4[(size_t)i * 4 + 1];
    float4 c = ea4[(size_t)i * 4 + 2];
    float4 d = ea4[(size_t)i * 4 + 3];
    sea4[(size_t)p * 4 + 0] = a;
    sea4[(size_t)p * 4 + 1] = b;
    sea4[(size_t)p * 4 + 2] = c;
    sea4[(size_t)p * 4 + 3] = d;
  }
  if (i < NEXP * 2 * D * D) {          // wpk[je][mat][col][k] = W_mat_je[k][col]
    int je  = i >> 13;
    int rem = i & 8191;
    int mat = rem >> 12;
    int cd  = rem & 4095;
    int col = cd >> 6, k = cd & 63;
    const float* W = mat ? ex_W2 : ex_W1;
    wpk[i] = f2bf(W[je * 4096 + k * 64 + col]);
  }
}

// ---------------- tkern: 2 nodes per wave, scalar-uniform edge stream ----------------

__global__ __launch_bounds__(256) void tkern(
    const float* __restrict__ x, const int* __restrict__ sorted_src,
    const float4* __restrict__ sea4, const int* __restrict__ offsets,
    const float* __restrict__ emb_We, float* __restrict__ agg0,
    unsigned int* __restrict__ Tp) {
  int lane = threadIdx.x & 63;
  int wv = threadIdx.x >> 6;
  int n0 = blockIdx.x * 8 + wv * 2;
  int n1 = n0 + 1;
  int st0 = __builtin_amdgcn_readfirstlane(offsets[n0]);
  int en0 = __builtin_amdgcn_readfirstlane(offsets[n0 + 1]);
  int en1 = __builtin_amdgcn_readfirstlane(offsets[n1 + 1]);
  int b0 = st0, b1 = en0;

  float tk0[DE], tk1[DE];
#pragma unroll
  for (int k = 0; k < DE; ++k) { tk0[k] = 0.f; tk1[k] = 0.f; }

  while (b0 < en0 || b1 < en1) {
    int e00 = (b0     < N_EDGES - 1) ? b0     : N_EDGES - 1;
    int e01 = (b0 + 1 < N_EDGES - 1) ? b0 + 1 : N_EDGES - 1;
    int e10 = (b1     < N_EDGES - 1) ? b1     : N_EDGES - 1;
    int e11 = (b1 + 1 < N_EDGES - 1) ? b1 + 1 : N_EDGES - 1;
    float m00 = (b0     < en0) ? 1.f : 0.f;
    float m01 = (b0 + 1 < en0) ? 1.f : 0.f;
    float m10 = (b1     < en1) ? 1.f : 0.f;
    float m11 = (b1 + 1 < en1) ? 1.f : 0.f;
    int s00 = sorted_src[e00];
    int s01 = sorted_src[e01];
    int s10 = sorted_src[e10];
    int s11 = sorted_src[e11];
    const float4* p00 = sea4 + ((size_t)e00 << 2);
    const float4* p01 = sea4 + ((size_t)e01 << 2);
    const float4* p10 = sea4 + ((size_t)e10 << 2);
    const float4* p11 = sea4 + ((size_t)e11 << 2);
    float4 a0 = p00[0], a1 = p00[1], a2 = p00[2], a3 = p00[3];
    float4 c0 = p01[0], c1 = p01[1], c2 = p01[2], c3 = p01[3];
    float4 d0 = p10[0], d1 = p10[1], d2 = p10[2], d3 = p10[3];
    float4 f0 = p11[0], f1 = p11[1], f2 = p11[2], f3 = p11[3];
    float x00 = x[(size_t)s00 * D + lane] * m00;
    float x01 = x[(size_t)s01 * D + lane] * m01;
    float x10 = x[(size_t)s10 * D + lane] * m10;
    float x11 = x[(size_t)s11 * D + lane] * m11;

    tk0[0]  += x00 * a0.x; tk0[1]  += x00 * a0.y; tk0[2]  += x00 * a0.z; tk0[3]  += x00 * a0.w;
    tk0[4]  += x00 * a1.x; tk0[5]  += x00 * a1.y; tk0[6]  += x00 * a1.z; tk0[7]  += x00 * a1.w;
    tk0[8]  += x00 * a2.x; tk0[9]  += x00 * a2.y; tk0[10] += x00 * a2.z; tk0[11] += x00 * a2.w;
    tk0[12] += x00 * a3.x; tk0[13] += x00 * a3.y; tk0[14] += x00 * a3.z; tk0[15] += x00 * a3.w;
    tk0[0]  += x01 * c0.x; tk0[1]  += x01 * c0.y; tk0[2]  += x01 * c0.z; tk0[3]  += x01 * c0.w;
    tk0[4]  += x01 * c1.x; tk0[5]  += x01 * c1.y; tk0[6]  += x01 * c1.z; tk0[7]  += x01 * c1.w;
    tk0[8]  += x01 * c2.x; tk0[9]  += x01 * c2.y; tk0[10] += x01 * c2.z; tk0[11] += x01 * c2.w;
    tk0[12] += x01 * c3.x; tk0[13] += x01 * c3.y; tk0[14] += x01 * c3.z; tk0[15] += x01 * c3.w;
    tk1[0]  += x10 * d0.x; tk1[1]  += x10 * d0.y; tk1[2]  += x10 * d0.z; tk1[3]  += x10 * d0.w;
    tk1[4]  += x10 * d1.x; tk1[5]  += x10 * d1.y; tk1[6]  += x10 * d1.z; tk1[7]  += x10 * d1.w;
    tk1[8]  += x10 * d2.x; tk1[9]  += x10 * d2.y; tk1[10] += x10 * d2.z; tk1[11] += x10 * d2.w;
    tk1[12] += x10 * d3.x; tk1[13] += x10 * d3.y; tk1[14] += x10 * d3.z; tk1[15] += x10 * d3.w;
    tk1[0]  += x11 * f0.x; tk1[1]  += x11 * f0.y; tk1[2]  += x11 * f0.z; tk1[3]  += x11 * f0.w;
    tk1[4]  += x11 * f1.x; tk1[5]  += x11 * f1.y; tk1[6]  += x11 * f1.z; tk1[7]  += x11 * f1.w;
    tk1[8]  += x11 * f2.x; tk1[9]  += x11 * f2.y; tk1[10] += x11 * f2.z; tk1[11] += x11 * f2.w;
    tk1[12] += x11 * f3.x; tk1[13] += x11 * f3.y; tk1[14] += x11 * f3.z; tk1[15] += x11 * f3.w;
    b0 += 2; b1 += 2;
  }

  {
    float av0 = 0.f, av1 = 0.f;
#pragma unroll
    for (int k = 0; k < DE; ++k) {
      float ewk = emb_We[k * D + lane];
      av0 += tk0[k] * ewk;
      av1 += tk1[k] * ewk;
    }
    agg0[(size_t)n0 * D + lane] = av0;
    agg0[(size_t)n1 * D + lane] = av1;
  }
  unsigned int* tp0 = Tp + (size_t)n0 * (D * DE / 2) + lane;
  unsigned int* tp1 = Tp + (size_t)n1 * (D * DE / 2) + lane;
#pragma unroll
  for (int j = 0; j < 8; ++j) {
    unsigned int pk0 = (unsigned int)f2bf(tk0[2 * j]) |
                       ((unsigned int)f2bf(tk0[2 * j + 1]) << 16);
    unsigned int pk1 = (unsigned int)f2bf(tk1[2 * j]) |
                       ((unsigned int)f2bf(tk1[2 * j + 1]) << 16);
    tp0[(size_t)j * D] = pk0;
    tp1[(size_t)j * D] = pk1;
  }
}

// ---------------- embedding GNN (j=0, exact f32, feeds routing) ----------------

__global__ __launch_bounds__(256) void gnn0_kernel(
    const float* __restrict__ x, const float* __restrict__ agg0,
    const float* __restrict__ W1, const float* __restrict__ W2,
    const float* __restrict__ bvv, float* __restrict__ graph_emb) {
  __shared__ __align__(16) float w1s[D * D];
  __shared__ __align__(16) float w2s[D * D];
  __shared__ __align__(16) float xs[D * D];
  __shared__ __align__(16) float as2[D * D];
  int b = blockIdx.x;
  int t = threadIdx.x;
  const float4* w1src = (const float4*)W1;
  const float4* w2src = (const float4*)W2;
  const float4* xsrc  = (const float4*)(x    + (size_t)b * D * D);
  const float4* asrc  = (const float4*)(agg0 + (size_t)b * D * D);
#pragma unroll
  for (int r = 0; r < 4; ++r) {
    ((float4*)w1s)[t + r * 256] = w1src[t + r * 256];
    ((float4*)w2s)[t + r * 256] = w2src[t + r * 256];
    ((float4*)xs)[t + r * 256]  = xsrc[t + r * 256];
    ((float4*)as2)[t + r * 256] = asrc[t + r * 256];
  }
  int w = t >> 6, lane = t & 63;
  float bias = bvv[lane];
  __syncthreads();
  float pool = 0.f;
#pragma unroll
  for (int q = 0; q < 4; ++q) {
    int n0 = w * 16 + q * 4;
    float a0 = bias, a1 = bias, a2 = bias, a3 = bias;
#pragma unroll 4
    for (int c4 = 0; c4 < 16; ++c4) {
      float4 x0 = *(const float4*)&xs[(n0 + 0) * D + c4 * 4];
      float4 x1 = *(const float4*)&xs[(n0 + 1) * D + c4 * 4];
      float4 x2 = *(const float4*)&xs[(n0 + 2) * D + c4 * 4];
      float4 x3 = *(const float4*)&xs[(n0 + 3) * D + c4 * 4];
      float4 g0 = *(const float4*)&as2[(n0 + 0) * D + c4 * 4];
      float4 g1 = *(const float4*)&as2[(n0 + 1) * D + c4 * 4];
      float4 g2 = *(const float4*)&as2[(n0 + 2) * D + c4 * 4];
      float4 g3 = *(const float4*)&as2[(n0 + 3) * D + c4 * 4];
      float w10 = w1s[(c4 * 4 + 0) * D + lane];
      float w11 = w1s[(c4 * 4 + 1) * D + lane];
      float w12 = w1s[(c4 * 4 + 2) * D + lane];
      float w13 = w1s[(c4 * 4 + 3) * D + lane];
      float w20 = w2s[(c4 * 4 + 0) * D + lane];
      float w21 = w2s[(c4 * 4 + 1) * D + lane];
      float w22 = w2s[(c4 * 4 + 2) * D + lane];
      float w23 = w2s[(c4 * 4 + 3) * D + lane];
      a0 += x0.x * w10 + x0.y * w11 + x0.z * w12 + x0.w * w13
          + g0.x * w20 + g0.y * w21 + g0.z * w22 + g0.w * w23;
      a1 += x1.x * w10 + x1.y * w11 + x1.z * w12 + x1.w * w13
          + g1.x * w20 + g1.y * w21 + g1.z * w22 + g1.w * w23;
      a2 += x2.x * w10 + x2.y * w11 + x2.z * w12 + x2.w * w13
          + g2.x * w20 + g2.y * w21 + g2.z * w22 + g2.w * w23;
      a3 += x3.x * w10 + x3.y * w11 + x3.z * w12 + x3.w * w13
          + g3.x * w20 + g3.y * w21 + g3.z * w22 + g3.w * w23;
    }
    pool += fmaxf(a0, 0.f) + fmaxf(a1, 0.f) + fmaxf(a2, 0.f) + fmaxf(a3, 0.f);
  }
  __syncthreads();
  xs[w * D + lane] = pool;
  __syncthreads();
  if (w == 0) {
    float s = xs[lane] + xs[D + lane] + xs[2 * D + lane] + xs[3 * D + lane];
    graph_emb[b * D + lane] = s * (1.f / 64.f);
  }
}

// ---------------- experts fused: contract (Tp -> LDS bf16) + MFMA + gating ----------------
// block = graph, 8 waves = 8 experts. Wave je contracts its expert's 64-node agg tile
// from Tp into als[je] (bf16, XOR-swizzled 16B slots), then MFMAs X@W1 + A@W2.
// No barrier needed between contract and MFMA: wave je writes/reads only als[je].
// mfma_f32_16x16x32_bf16: A row=lane&15, k=(lane>>4)*8+i ; C/D col=lane&15, row=(lane>>4)*4+reg

__global__ __launch_bounds__(512) void expert_kernel(
    const float* __restrict__ x, const unsigned int* __restrict__ Tp,
    const float* __restrict__ ex_We, const unsigned short* __restrict__ wpk,
    const float* __restrict__ ex_b, const float* __restrict__ ex_Wout,
    const float* __restrict__ ex_bout,
    const float* __restrict__ graph_emb, const float* __restrict__ Wg,
    const float* __restrict__ bg, float* __restrict__ out) {
  __shared__ __align__(16) short xls[4096];        // X tile bf16, swizzled (8 KB)
  __shared__ __align__(16) short als[NEXP * 4096]; // per-expert agg tiles (64 KB)
  __shared__ float pg[NEXP];
  __shared__ float lg[NEXP];
  int g = blockIdx.x;
  int t = threadIdx.x;
  // stage X tile: f32 -> bf16, swizzled (thread t handles 16B = 8 bf16)
  {
    const float4* xp = (const float4*)(x + (size_t)g * 4096 + (size_t)t * 8);
    float4 va = xp[0], vb = xp[1];
    short8v pk;
    pk[0] = (short)f2bf(va.x); pk[1] = (short)f2bf(va.y);
    pk[2] = (short)f2bf(va.z); pk[3] = (short)f2bf(va.w);
    pk[4] = (short)f2bf(vb.x); pk[5] = (short)f2bf(vb.y);
    pk[6] = (short)f2bf(vb.z); pk[7] = (short)f2bf(vb.w);
    int row = t >> 3, slot = t & 7;
    *(short8v*)((char*)xls + (((row << 3) + (slot ^ (row & 7))) << 4)) = pk;
  }

  int je = t >> 6;
  int lane = t & 63;

  // ---- contract phase: wave je builds als[je] for this graph's 64 nodes ----
  {
    float wr[DE];
#pragma unroll
    for (int k = 0; k < DE; ++k) wr[k] = ex_We[(size_t)je * DE * D + k * D + lane];
    char* abase = (char*)als + (size_t)je * 8192;
    int slot = lane >> 3;
    int within = (lane & 7) << 1;
    for (int i = 0; i < D; i += 2) {
      int nA = g * D + i, nB = nA + 1;
      const unsigned int* ta = Tp + (size_t)nA * 512 + lane;
      const unsigned int* tb = Tp + (size_t)nB * 512 + lane;
      unsigned int pa0 = ta[0],   pa1 = ta[64],  pa2 = ta[128], pa3 = ta[192];
      unsigned int pa4 = ta[256], pa5 = ta[320], pa6 = ta[384], pa7 = ta[448];
      unsigned int pb0 = tb[0],   pb1 = tb[64],  pb2 = tb[128], pb3 = tb[192];
      unsigned int pb4 = tb[256], pb5 = tb[320], pb6 = tb[384], pb7 = tb[448];
      float sA, sB;
      sA  = __uint_as_float(pa0 << 16)         * wr[0];
      sA += __uint_as_float(pa0 & 0xFFFF0000u) * wr[1];
      sA += __uint_as_float(pa1 << 16)         * wr[2];
      sA += __uint_as_float(pa1 & 0xFFFF0000u) * wr[3];
      sA += __uint_as_float(pa2 << 16)         * wr[4];
      sA += __uint_as_float(pa2 & 0xFFFF0000u) * wr[5];
      sA += __uint_as_float(pa3 << 16)         * wr[6];
      sA += __uint_as_float(pa3 & 0xFFFF0000u) * wr[7];
      sA += __uint_as_float(pa4 << 16)         * wr[8];
      sA += __uint_as_float(pa4 & 0xFFFF0000u) * wr[9];
      sA += __uint_as_float(pa5 << 16)         * wr[10];
      sA += __uint_as_float(pa5 & 0xFFFF0000u) * wr[11];
      sA += __uint_as_float(pa6 << 16)         * wr[12];
      sA += __uint_as_float(pa6 & 0xFFFF0000u) * wr[13];
      sA += __uint_as_float(pa7 << 16)         * wr[14];
      sA += __uint_as_float(pa7 & 0xFFFF0000u) * wr[15];
      sB  = __uint_as_float(pb0 << 16)         * wr[0];
      sB += __uint_as_float(pb0 & 0xFFFF0000u) * wr[1];
      sB += __uint_as_float(pb1 << 16)         * wr[2];
      sB += __uint_as_float(pb1 & 0xFFFF0000u) * wr[3];
      sB += __uint_as_float(pb2 << 16)         * wr[4];
      sB += __uint_as_float(pb2 & 0xFFFF0000u) * wr[5];
      sB += __uint_as_float(pb3 << 16)         * wr[6];
      sB += __uint_as_float(pb3 & 0xFFFF0000u) * wr[7];
      sB += __uint_as_float(pb4 << 16)         * wr[8];
      sB += __uint_as_float(pb4 & 0xFFFF0000u) * wr[9];
      sB += __uint_as_float(pb5 << 16)         * wr[10];
      sB += __uint_as_float(pb5 & 0xFFFF0000u) * wr[11];
      sB += __uint_as_float(pb6 << 16)         * wr[12];
      sB += __uint_as_float(pb6 & 0xFFFF0000u) * wr[13];
      sB += __uint_as_float(pb7 << 16)         * wr[14];
      sB += __uint_as_float(pb7 & 0xFFFF0000u) * wr[15];
      // row-writes: 128B contiguous per row -> conflict-free; slots XOR-swizzled by row
      *(short*)(abase + (i    ) * 128 + ((slot ^ ( i      & 7)) << 4) + within) = (short)f2bf(sA);
      *(short*)(abase + (i + 1) * 128 + ((slot ^ ((i + 1) & 7)) << 4) + within) = (short)f2bf(sB);
    }
  }
  __syncthreads();   // X tile ready (als[je] is same-wave, ordered by lgkmcnt)

  int r = lane & 15, q = lane >> 4;
  const short* B1 = (const short*)(wpk + (size_t)je * 2 * 4096);
  const short* B2 = B1 + 4096;
  char* abase = (char*)als + (size_t)je * 8192;

  floatx4 acc[4][4];
#pragma unroll
  for (int i = 0; i < 4; ++i)
#pragma unroll
    for (int j = 0; j < 4; ++j) acc[i][j] = (floatx4){0.f, 0.f, 0.f, 0.f};

  // phase 1: X(LDS) @ W1(global)
#pragma unroll
  for (int kk = 0; kk < 2; ++kk) {
    int ko = kk * 32 + q * 8;
    short8v af[4], bf[4];
#pragma unroll
    for (int rt = 0; rt < 4; ++rt) {
      int row = rt * 16 + r;
      int slot = kk * 4 + q;
      af[rt] = *(const short8v*)((char*)xls + (((row << 3) + (slot ^ (row & 7))) << 4));
    }
#pragma unroll
    for (int ct = 0; ct < 4; ++ct) bf[ct] = *(const short8v*)(B1 + (ct * 16 + r) * D + ko);
#pragma unroll
    for (int rt = 0; rt < 4; ++rt)
#pragma unroll
      for (int ct = 0; ct < 4; ++ct)
        acc[rt][ct] = __builtin_amdgcn_mfma_f32_16x16x32_bf16(af[rt], bf[ct], acc[rt][ct], 0, 0, 0);
  }
  // phase 2: AGG(LDS, own-expert tile) @ W2(global)
#pragma unroll
  for (int kk = 0; kk < 2; ++kk) {
    int ko = kk * 32 + q * 8;
    short8v af[4], bf[4];
#pragma unroll
    for (int rt = 0; rt < 4; ++rt) {
      int row = rt * 16 + r;
      int slot = kk * 4 + q;
      af[rt] = *(const short8v*)(abase + (row << 7) + ((slot ^ (row & 7)) << 4));
    }
#pragma unroll
    for (int ct = 0; ct < 4; ++ct) bf[ct] = *(const short8v*)(B2 + (ct * 16 + r) * D + ko);
#pragma unroll
    for (int rt = 0; rt < 4; ++rt)
#pragma unroll
      for (int ct = 0; ct < 4; ++ct)
        acc[rt][ct] = __builtin_amdgcn_mfma_f32_16x16x32_bf16(af[rt], bf[ct], acc[rt][ct], 0, 0, 0);
  }

  // epilogue: relu(+bias), pool over 64 rows, dot with Wout, mean, +bout -> LDS
  float o = 0.f;
#pragma unroll
  for (int ct = 0; ct < 4; ++ct) {
    float bcol = ex_b[je * D + ct * 16 + r];
    float s = 0.f;
#pragma unroll
    for (int rt = 0; rt < 4; ++rt)
#pragma unroll
      for (int rg = 0; rg < 4; ++rg) s += fmaxf(acc[rt][ct][rg] + bcol, 0.f);
    s += __shfl_xor(s, 16);
    s += __shfl_xor(s, 32);
    o += s * ex_Wout[je * D + ct * 16 + r];
  }
#pragma unroll
  for (int off = 8; off >= 1; off >>= 1) o += __shfl_xor(o, off);
  if (lane == 0) pg[je] = o * (1.f / 64.f) + ex_bout[je];
  __syncthreads();

  // fused gating (exact f32): reuse xls as float scratch for graph_emb row
  float* es = (float*)xls;
  if (t < 64) es[t] = graph_emb[g * D + t];
  __syncthreads();
  if (t < NEXP) {
    float v = bg[t];
    for (int d = 0; d < D; ++d) v += es[d] * Wg[d * NEXP + t];
    lg[t] = v;
  }
  __syncthreads();
  if (t < NEXP) {
    float l[NEXP];
    float mx = -1e30f;
#pragma unroll
    for (int e = 0; e < NEXP; ++e) { l[e] = lg[e]; mx = fmaxf(mx, l[e]); }
    float p[NEXP];
    float sum = 0.f;
#pragma unroll
    for (int e = 0; e < NEXP; ++e) { p[e] = expf(l[e] - mx); sum += p[e]; }
    float inv = 1.f / sum;
#pragma unroll
    for (int e = 0; e < NEXP; ++e) p[e] *= inv;
    out[NB + g * NEXP + t] = p[t];
    if (t == 0) {
      int i1 = -1; float v1 = -1e30f;
#pragma unroll
      for (int e = 0; e < NEXP; ++e) if (p[e] > v1) { v1 = p[e]; i1 = e; }
      int i2 = -1; float v2 = -1e30f;
#pragma unroll
      for (int e = 0; e < NEXP; ++e) if (e != i1 && p[e] > v2) { v2 = p[e]; i2 = e; }
      float rr = expf(v2 - v1);
      float n1 = 1.f / (1.f + rr);
      float n2 = rr / (1.f + rr);
      out[g] = n1 * pg[i1] + n2 * pg[i2];
    }
  }
}

// ---------------- launch ----------------

extern "C" void kernel_launch(void* const* d_in, const int* in_sizes, int n_in,
                              void* d_out, int out_size, void* d_ws, size_t ws_size,
                              hipStream_t stream) {
  const float* x         = (const float*)d_in[0];
  const float* edge_attr = (const float*)d_in[1];
  const float* emb_We    = (const float*)d_in[2];
  const float* emb_W1    = (const float*)d_in[3];
  const float* emb_W2    = (const float*)d_in[4];
  const float* emb_b     = (const float*)d_in[5];
  const float* Wg        = (const float*)d_in[6];
  const float* bg        = (const float*)d_in[7];
  const float* ex_We     = (const float*)d_in[8];
  const float* ex_W1     = (const float*)d_in[9];
  const float* ex_W2     = (const float*)d_in[10];
  const float* ex_b      = (const float*)d_in[11];
  const float* ex_Wout   = (const float*)d_in[12];
  const float* ex_bout   = (const float*)d_in[13];
  const int* edge_src    = (const int*)d_in[14];
  const int* edge_dst    = (const int*)d_in[15];

  char* p = (char*)d_ws;
  auto alloc = [&](size_t bytes) {
    char* q = p;
    p += (bytes + 255) & ~(size_t)255;
    return q;
  };
  int*   counts     = (int*)alloc((size_t)N_NODES * 4);
  int*   offsets    = (int*)alloc((size_t)(N_NODES + 1) * 4);
  int*   cursor     = (int*)alloc((size_t)N_NODES * 4);
  int*   bsums      = (int*)alloc(128 * 4);
  int*   sorted_src = (int*)alloc((size_t)N_EDGES * 4);
  float* sorted_ea  = (float*)alloc((size_t)N_EDGES * DE * 4);
  unsigned int* Tp  = (unsigned int*)alloc((size_t)N_NODES * (D * DE / 2) * 4);  // 64 MB
  float* agg0       = (float*)alloc((size_t)N_NODES * D * 4);
  unsigned short* wpk = (unsigned short*)alloc((size_t)NEXP * 2 * D * D * 2);
  float* graph_emb  = (float*)alloc((size_t)NB * D * 4);

  hipMemsetAsync(counts, 0, (size_t)N_NODES * 4, stream);
  hist_kernel<<<N_EDGES / 256, 256, 0, stream>>>(edge_dst, counts);
  scan1_kernel<<<N_NODES / 256, 256, 0, stream>>>(counts, offsets, bsums);
  scan2_kernel<<<1, 128, 0, stream>>>(bsums);
  scan3_kernel<<<N_NODES / 256, 256, 0, stream>>>(offsets, bsums, cursor);
  scatter_kernel<<<N_EDGES / 256, 256, 0, stream>>>(edge_dst, edge_src,
                                                    (const float4*)edge_attr, cursor,
                                                    sorted_src, (float4*)sorted_ea,
                                                    ex_W1, ex_W2, wpk);
  tkern<<<N_NODES / 8, 256, 0, stream>>>(x, sorted_src, (const float4*)sorted_ea,
                                         offsets, emb_We, agg0, Tp);
  gnn0_kernel<<<NB, 256, 0, stream>>>(x, agg0, emb_W1, emb_W2, emb_b, graph_emb);
  expert_kernel<<<NB, 512, 0, stream>>>(x, Tp, ex_We, wpk, ex_b, ex_Wout, ex_bout,
                                        graph_emb, Wg, bg, (float*)d_out);
}